// Round 5
// baseline (389.527 us; speedup 1.0000x reference)
//
#include <hip/hip_runtime.h>
#include <hip/hip_bf16.h>

typedef __bf16 bf16x8 __attribute__((ext_vector_type(8)));
typedef __bf16 bf16x4 __attribute__((ext_vector_type(4)));
typedef float f32x4 __attribute__((ext_vector_type(4)));

#define MFMA(a, b, c) __builtin_amdgcn_mfma_f32_16x16x32_bf16(a, b, c, 0, 0, 0)

// ws layout (bf16 elem offsets) — weights in MFMA B-fragment order:
// frag[(nt*nKT + kt)*64 + lane][j] = W[kt*32 + (lane>>4)*8 + j][nt*16 + (lane&15)]
constexpr int MP_OFF = 0;
constexpr int W1_OFF = 8192;
constexpr int W2_OFF = 49152;
constexpr int W3_OFF = 114688;
constexpr int W4_OFF = 155648;
constexpr int WS_TOTAL = 221184;
constexpr size_t WS_BYTES = (size_t)WS_TOTAL * 2;

__device__ __forceinline__ float ldf(const void* p, int i, bool f32) {
    return f32 ? ((const float*)p)[i] : (float)(((const __bf16*)p)[i]);
}
__device__ __forceinline__ int geti(const int* p, int i, bool i64) {
    return p[i64 ? 2 * i : i];
}

// Read-side swizzle with fused dtype self-detect (fp32 misread as bf16 shows
// exponent-0xFF halfwords). Block 0 also publishes flags for gn_main.
__global__ void swz(const void* __restrict__ mp, const void* __restrict__ w1,
                    const void* __restrict__ w2, const void* __restrict__ w3,
                    const void* __restrict__ w4, __bf16* __restrict__ ws,
                    const unsigned short* __restrict__ uo, int* __restrict__ flags) {
    __shared__ int s_fw, s_fi;
    int tid = threadIdx.x;
    if (tid == 0) { s_fw = 0; s_fi = 0; }
    __syncthreads();
    const unsigned short* uw = (const unsigned short*)w2;
    int d = 0;
    for (int i = tid; i < 8192; i += 256)
        d |= (((uw[i] >> 7) & 0xFF) == 0xFF) ? 1 : 0;
    if (d) atomicOr(&s_fw, 1);
    if (blockIdx.x == 0) {
        int d0 = 0;
        for (int i = tid; i < 8192; i += 256)
            d0 |= (((uo[i] >> 7) & 0xFF) == 0xFF) ? 1 : 0;
        if (d0) atomicOr(&s_fi, 1);
    }
    __syncthreads();
    bool f32 = s_fw != 0;
    if (blockIdx.x == 0 && tid == 0) { flags[0] = s_fi; flags[1] = s_fw; }

    int idx = blockIdx.x * blockDim.x + tid;
    if (idx >= WS_TOTAL) return;
    const void* src;
    int base, local, nKT, nsh, style, K;
    if (idx < W1_OFF)      { src = mp; base = MP_OFF; local = idx;          nKT = 2; nsh = 7; style = 0; K = 46; }
    else if (idx < W2_OFF) { src = w1; base = W1_OFF; local = idx - W1_OFF; nKT = 5; nsh = 8; style = 1; K = 157; }
    else if (idx < W3_OFF) { src = w2; base = W2_OFF; local = idx - W2_OFF; nKT = 8; nsh = 8; style = 0; K = 256; }
    else if (idx < W4_OFF) { src = w3; base = W3_OFF; local = idx - W3_OFF; nKT = 5; nsh = 8; style = 1; K = 157; }
    else                   { src = w4; base = W4_OFF; local = idx - W4_OFF; nKT = 8; nsh = 8; style = 0; K = 256; }
    int N = 1 << nsh;
    int kp = local >> nsh, n = local & (N - 1);
    int ks = kp;
    bool ok = true;
    if (style == 1) { if (kp >= 32) ks = kp - 3; else if (kp >= 29) ok = false; }
    if (ks >= K) ok = false;
    float v = ok ? ldf(src, ks * N + n, f32) : 0.f;
    int dst = ((n >> 4) * nKT + (kp >> 5)) * 512 +
              (((((kp >> 3) & 3)) << 4) | (n & 15)) * 8 + (kp & 7);
    ws[base + dst] = (__bf16)v;
}

// Direct B-fragment gather fallback (ws too small). Same lane mapping as A-frag.
__device__ __forceinline__ bf16x8 gatherB(const void* W, bool f32, int style,
                                          int K, int N, int k0, int n, int q) {
    bf16x8 r;
#pragma unroll
    for (int j = 0; j < 8; ++j) {
        int k = k0 + q * 8 + j;
        bool ok = true;
        if (style == 1) { if (k >= 32) k -= 3; else if (k >= 29) ok = false; }
        if (k >= K) ok = false;
        float v = ok ? ldf(W, k * N + n, f32) : 0.f;
        r[j] = (__bf16)v;
    }
    return r;
}

// LDS budget 38,256 B -> 4 blocks/CU (round-1 parts only: NO kt0 recompute,
// NO '-1' s_inp indexing, NO int-aliasing of LDS — rounds 3/4 showed one of
// those constructs generates ~125 KB/block scratch traffic).
//   s_union[6144] (12,288 B):
//     [0..4096): edge-A frags (PC=4) during stage1 phase; h frags (MTN=1,
//                1 mt x 8 ht x 512) during P-loop
//     [4096..6016): rowbuf 16x120 (rb) — dead after last buildA
//   s_inp[12800] (25,600 B): FULL 5-kt plane incl. kt0 (round-1 style)
//   s_q[32] (128 B); s_ints[60] (240 B, separate — no aliasing)
template <int PC, int PBASE>
__device__ __forceinline__ void buildA(__bf16* sA, const __bf16* rb, const int* s_esrc,
                                       const int* s_pid0, const int* s_pid1, int tid) {
    for (int i = tid; i < 16 * PC * 8; i += 512) {
        int t = i >> 6, lanep = i & 63;
        int oct = ((t & 1) << 2) | (lanep >> 4);
        int r = (t >> 1) * 16 + (lanep & 15);
        int lb = r / PC, p = PBASE + r % PC;
        const __bf16* row = rb + lb * 120;
        bf16x8 v;
#pragma unroll
        for (int j = 0; j < 8; ++j) {
            int k = oct * 8 + j;
            __bf16 x = (__bf16)0.f;
            if (k < 10) x = row[k];
            else if (k < 14) x = row[85 + (k - 10)];
            else if (k < 16) x = row[89 + ((k == 14) ? s_pid0[p] : s_pid1[p])];
            else if (k < 31) x = row[10 + s_esrc[p] * 15 + (k - 16)];
            else if (k < 46) x = row[10 + (p >> 2) * 15 + (k - 31)];
            v[j] = x;
        }
        *(bf16x8*)(sA + t * 512 + lanep * 8) = v;
    }
}

// stage1: A=edges, B=mp_w frags; 8 waves x 1 nt. PC=4: one pass per object o,
// quad (4 rows) = the 4 incoming edges of o for one lb -> sum = agg.
// Writes the round-1 5-kt s_inp layout (kt = kk>>5, kt0 stored separately).
template <int PC, int PBASE, bool DW>
__device__ __forceinline__ void stage1(const __bf16* Wf, const void* Wn, bool fW,
                                       const void* mp_b, const __bf16* sA,
                                       __bf16* s_inp, int wave, int lane) {
    int q = lane >> 4, c = lane & 15;
    int nt = wave;
    float mb = ldf(mp_b, nt * 16 + c, fW);
    bf16x8 bw[2];
#pragma unroll
    for (int kt = 0; kt < 2; ++kt) {
        if constexpr (DW) bw[kt] = gatherB(Wn, fW, 0, 46, 128, kt * 32, nt * 16 + c, q);
        else bw[kt] = *(const bf16x8*)(Wf + (nt * 2 + kt) * 512 + lane * 8);
    }
    f32x4 zero4 = {0.f, 0.f, 0.f, 0.f};
#pragma unroll
    for (int m = 0; m < PC; ++m) {
        f32x4 acc = zero4;
#pragma unroll
        for (int kt = 0; kt < 2; ++kt) {
            bf16x8 a = *(const bf16x8*)(sA + (m * 2 + kt) * 512 + lane * 8);
            acc = MFMA(a, bw[kt], acc);
        }
        float sum = 0.f;
#pragma unroll
        for (int rr = 0; rr < 4; ++rr) {
            float z = acc[rr] + mb;
            sum += (z > 0.f) ? z : 0.f;
        }
        int r0 = m * 16 + q * 4;          // PC=4: quad = one lb's 4 edges
        int lb = r0 / PC;
        int o = (PBASE + r0 % PC) >> 2;   // constant per pass
        int rinp = lb * 5 + o;
        int kk = 32 + nt * 16 + c;        // 32..159 -> kt 1..4
        s_inp[((rinp >> 4) * 5 + (kk >> 5)) * 512 +
              ((((kk & 31) >> 3) << 4) + (rinp & 15)) * 8 + (kk & 7)] = (__bf16)sum;
    }
}

// stage2 SWAPPED: D'[hcol][row] = MFMA(A=W1-frag, B=inp-frag); kt outer, b-frags
// read once per kt (shared across both n). All 5 kt read from s_inp (stored).
template <int MTN, bool DW>
__device__ __forceinline__ void stage2s(int mbase, const __bf16* Wf, const void* Wn,
                                        bool fW, const void* Ba, __bf16* s_h,
                                        const __bf16* s_inp, int wave, int lane) {
    int q = lane >> 4, c = lane & 15;
    f32x4 zero4 = {0.f, 0.f, 0.f, 0.f};
    f32x4 acc[2][MTN];
#pragma unroll
    for (int n = 0; n < 2; ++n)
#pragma unroll
        for (int m = 0; m < MTN; ++m) acc[n][m] = zero4;
#pragma unroll
    for (int kt = 0; kt < 5; ++kt) {
        bf16x8 b[MTN];
#pragma unroll
        for (int m = 0; m < MTN; ++m)
            b[m] = *(const bf16x8*)(s_inp + ((mbase + m) * 5 + kt) * 512 + lane * 8);
#pragma unroll
        for (int n = 0; n < 2; ++n) {
            int ht = wave * 2 + n;
            bf16x8 aw;
            if constexpr (DW) aw = gatherB(Wn, fW, 1, 157, 256, kt * 32, ht * 16 + c, q);
            else aw = *(const bf16x8*)(Wf + (ht * 5 + kt) * 512 + lane * 8);
#pragma unroll
            for (int m = 0; m < MTN; ++m) acc[n][m] = MFMA(aw, b[m], acc[n][m]);
        }
    }
    float bias_r[2][4];
#pragma unroll
    for (int n = 0; n < 2; ++n)
#pragma unroll
        for (int rg = 0; rg < 4; ++rg)
            bias_r[n][rg] = ldf(Ba, (wave * 2 + n) * 16 + q * 4 + rg, fW);
#pragma unroll
    for (int n = 0; n < 2; ++n) {
        int ht = wave * 2 + n;
#pragma unroll
        for (int m = 0; m < MTN; ++m) {
            bf16x4 hv;
#pragma unroll
            for (int rg = 0; rg < 4; ++rg) {
                float z = acc[n][m][rg] + bias_r[n][rg];
                hv[rg] = (__bf16)((z > 0.f) ? z : 0.f);
            }
            *(bf16x4*)(s_h + (m * 8 + (ht >> 1)) * 512 +
                       ((((ht & 1) * 2 + (q >> 1)) << 4) | c) * 8 + ((q & 1) << 2)) = hv;
        }
    }
}

// stage3 SWAPPED: D'[ncol][row] = MFMA(A=W2-frag, B=h-frag); kt outer, h b-frags
// read once per kt (shared across both n).
template <int MTN, bool DW>
__device__ __forceinline__ void stage3s(int mbase, const __bf16* Wf, const void* Wn,
                                        bool fW, const void* Bb, const void* Rh,
                                        const __bf16* s_h, float* s_qp, int wave, int lane) {
    int q = lane >> 4, c = lane & 15;
    f32x4 zero4 = {0.f, 0.f, 0.f, 0.f};
    f32x4 acc[2][MTN];
#pragma unroll
    for (int n = 0; n < 2; ++n)
#pragma unroll
        for (int m = 0; m < MTN; ++m) acc[n][m] = zero4;
#pragma unroll
    for (int kt = 0; kt < 8; ++kt) {
        bf16x8 b[MTN];
#pragma unroll
        for (int m = 0; m < MTN; ++m)
            b[m] = *(const bf16x8*)(s_h + (m * 8 + kt) * 512 + lane * 8);
#pragma unroll
        for (int n = 0; n < 2; ++n) {
            int nt = wave * 2 + n;
            bf16x8 aw;
            if constexpr (DW) aw = gatherB(Wn, fW, 0, 256, 256, kt * 32, nt * 16 + c, q);
            else aw = *(const bf16x8*)(Wf + (nt * 8 + kt) * 512 + lane * 8);
#pragma unroll
            for (int m = 0; m < MTN; ++m) acc[n][m] = MFMA(aw, b[m], acc[n][m]);
        }
    }
    float bias_r[2][4], rho_r[2][4];
#pragma unroll
    for (int n = 0; n < 2; ++n)
#pragma unroll
        for (int rg = 0; rg < 4; ++rg) {
            int ncol = (wave * 2 + n) * 16 + q * 4 + rg;
            bias_r[n][rg] = ldf(Bb, ncol, fW);
            rho_r[n][rg] = ldf(Rh, ncol, fW);
        }
    float rowsum[MTN];
#pragma unroll
    for (int m = 0; m < MTN; ++m) rowsum[m] = 0.f;
#pragma unroll
    for (int n = 0; n < 2; ++n)
#pragma unroll
        for (int m = 0; m < MTN; ++m)
#pragma unroll
            for (int rg = 0; rg < 4; ++rg) {
                float z = acc[n][m][rg] + bias_r[n][rg];
                z = (z > 0.f) ? z : 0.f;
                rowsum[m] += z * rho_r[n][rg];
            }
#pragma unroll
    for (int m = 0; m < MTN; ++m) {
        float v = rowsum[m];
        v += __shfl_xor(v, 16);
        v += __shfl_xor(v, 32);
        if (q == 0) {
            int r0 = (mbase + m) * 16 + c;  // rinp = b*5+o
            atomicAdd(&s_qp[r0 / 5], v);
        }
    }
}

template <bool DW>
__global__ __launch_bounds__(512, 6) void gn_main(
    const void* __restrict__ obs, const void* __restrict__ act,
    const void* __restrict__ ag, const void* __restrict__ g,
    const void* __restrict__ mp_b, const void* __restrict__ b1,
    const void* __restrict__ b2, const void* __restrict__ b3,
    const void* __restrict__ b4, const void* __restrict__ rw1,
    const void* __restrict__ rb1, const void* __restrict__ rw2,
    const void* __restrict__ rb2, const int* __restrict__ eA,
    const int* __restrict__ eB, const int* __restrict__ pred_ids,
    const int* __restrict__ incoming, const __bf16* __restrict__ wsW,
    const void* __restrict__ mp_w, const void* __restrict__ w1,
    const void* __restrict__ w2, const void* __restrict__ w3,
    const void* __restrict__ w4, const int* __restrict__ flags,
    float* __restrict__ out, int Btot) {
    __shared__ __align__(16) __bf16 s_union[6144];
    __shared__ __align__(16) __bf16 s_inp[12800];
    __shared__ __align__(16) float s_q[32];
    __shared__ int s_esrc[20], s_pid0[20], s_pid1[20];

    int tid = threadIdx.x, lane = tid & 63, wave = tid >> 6;
    int b0 = blockIdx.x * 16;
    __bf16* rb = s_union + 4096;  // [4096..6016): dead after last buildA

    // ---- dtype flags ----
    bool fI, fW;
    if constexpr (DW) {
        const unsigned short* uo = (const unsigned short*)obs;
        const unsigned short* uw = (const unsigned short*)w2;
        int d0 = 0, d1 = 0;
        for (int i = lane; i < 8192; i += 64) {
            if (((uo[i] >> 7) & 0xFF) == 0xFF) d0 = 1;
            if (((uw[i] >> 7) & 0xFF) == 0xFF) d1 = 1;
        }
        fI = __ballot(d0) != 0;
        fW = __ballot(d1) != 0;
    } else {
        fI = flags[0] != 0;
        fW = flags[1] != 0;
    }

    // ---- int width + src/dst disambiguation ----
    bool i64_i = (incoming[1] == 0);
    bool i64_p = (pred_ids[1] == 0);
    bool i64_e = (eA[9] == 0);
    const int* es = (geti(eA, 4, i64_e) == 1) ? eA : eB;

    if (tid < 20) {
        int e = geti(incoming, tid, i64_i);  // tid = o*4+j; edge p=tid has dst o=tid/4
        s_esrc[tid] = geti(es, e, i64_e);
        s_pid0[tid] = geti(pred_ids, 2 * e, i64_p);
        s_pid1[tid] = geti(pred_ids, 2 * e + 1, i64_p);
    }

    for (int i = tid; i < 16 * 120; i += 512) {
        int lb = i / 120, cidx = i % 120;
        int bg = b0 + lb;
        float v = 0.f;
        if (cidx < 85) v = ldf(obs, bg * 85 + cidx, fI);
        else if (cidx < 89) v = ldf(act, bg * 4 + (cidx - 85), fI);
        else if (cidx < 119) {
            int t = cidx - 89;
            v = ldf(g, bg * 30 + t, fI) - ldf(ag, bg * 30 + t, fI);
        }
        rb[i] = (__bf16)v;
    }
    __syncthreads();

    // inp kt=0 plane (k<32), conflict-free mapping (round-1 code)
    for (int i = tid; i < 320; i += 512) {
        int mt = i >> 6, lanep = i & 63;
        int oct = lanep >> 4;
        int r = mt * 16 + (lanep & 15);
        int lb = r / 5, o = r % 5;
        const __bf16* row = rb + lb * 120;
        bf16x8 v;
#pragma unroll
        for (int j = 0; j < 8; ++j) {
            int k = oct * 8 + j;
            __bf16 x = (__bf16)0.f;
            if (k < 4) x = row[85 + k];
            else if (k < 14) x = row[k - 4];
            else if (k < 29) x = row[10 + o * 15 + (k - 14)];
            v[j] = x;
        }
        *(bf16x8*)(s_inp + mt * 2560 + lanep * 8) = v;
    }
    buildA<4, 0>(s_union, rb, s_esrc, s_pid0, s_pid1, tid);
    __syncthreads();
    stage1<4, 0, DW>(wsW + MP_OFF, mp_w, fW, mp_b, s_union, s_inp, wave, lane);
    __syncthreads();
    buildA<4, 4>(s_union, rb, s_esrc, s_pid0, s_pid1, tid);
    __syncthreads();
    stage1<4, 4, DW>(wsW + MP_OFF, mp_w, fW, mp_b, s_union, s_inp, wave, lane);
    __syncthreads();
    buildA<4, 8>(s_union, rb, s_esrc, s_pid0, s_pid1, tid);
    __syncthreads();
    stage1<4, 8, DW>(wsW + MP_OFF, mp_w, fW, mp_b, s_union, s_inp, wave, lane);
    __syncthreads();
    buildA<4, 12>(s_union, rb, s_esrc, s_pid0, s_pid1, tid);
    __syncthreads();
    stage1<4, 12, DW>(wsW + MP_OFF, mp_w, fW, mp_b, s_union, s_inp, wave, lane);
    __syncthreads();
    buildA<4, 16>(s_union, rb, s_esrc, s_pid0, s_pid1, tid);
    __syncthreads();
    stage1<4, 16, DW>(wsW + MP_OFF, mp_w, fW, mp_b, s_union, s_inp, wave, lane);
    if (tid < 32) s_q[tid] = 0.f;
    __syncthreads();

    for (int P = 0; P < 2; ++P) {
        const __bf16* Wa = wsW + (P ? W3_OFF : W1_OFF);
        const __bf16* Wb = wsW + (P ? W4_OFF : W2_OFF);
        const void* Wan = P ? w3 : w1;
        const void* Wbn = P ? w4 : w2;
        const void* ba = P ? b3 : b1;
        const void* bb = P ? b4 : b2;
        const void* rho = P ? rw2 : rw1;
        float* qp = s_q + P * 16;
#pragma unroll 1
        for (int mb = 0; mb < 5; ++mb) {
            stage2s<1, DW>(mb, Wa, Wan, fW, ba, s_union, s_inp, wave, lane);
            __syncthreads();
            stage3s<1, DW>(mb, Wb, Wbn, fW, bb, rho, s_union, qp, wave, lane);
            __syncthreads();
        }
    }

    if (tid < 16) {
        out[b0 + tid] = s_q[tid] + ldf(rb1, 0, fW);
        out[Btot + b0 + tid] = s_q[16 + tid] + ldf(rb2, 0, fW);
    }
}

extern "C" void kernel_launch(void* const* d_in, const int* in_sizes, int n_in,
                              void* d_out, int out_size, void* d_ws, size_t ws_size,
                              hipStream_t stream) {
    int B = out_size / 2;  // 16384

    const void *obs = nullptr, *act = nullptr, *ag = nullptr, *g = nullptr;
    const void *mp_w = nullptr, *mp_b = nullptr;
    const void *w1 = nullptr, *b1 = nullptr, *w2 = nullptr, *b2 = nullptr;
    const void *w3 = nullptr, *b3 = nullptr, *w4 = nullptr, *b4 = nullptr;
    const void *rw1 = nullptr, *rb1 = nullptr, *rw2 = nullptr, *rb2 = nullptr;
    const int *eA = nullptr, *eB = nullptr, *pred = nullptr, *inc = nullptr;
    int c30 = 0, c256 = 0, c1 = 0, c40k = 0, c65k = 0, c20 = 0;
    for (int i = 0; i < n_in; ++i) {
        int sz = in_sizes[i];
        const void* p = d_in[i];
        if (sz == B * 85) obs = p;
        else if (sz == B * 30) { if (c30++ == 0) ag = p; else g = p; }
        else if (sz == 5888) mp_w = p;
        else if (sz == 128) mp_b = p;
        else if (sz == 40192) { if (c40k++ == 0) w1 = p; else w3 = p; }
        else if (sz == 65536 || sz == B * 4) {
            int c = c65k++;
            if (c == 0) act = p; else if (c == 1) w2 = p; else w4 = p;
        }
        else if (sz == 256) {
            int c = c256++;
            if (c == 0) b1 = p; else if (c == 1) b2 = p; else if (c == 2) b3 = p;
            else if (c == 3) b4 = p; else if (c == 4) rw1 = p; else rw2 = p;
        }
        else if (sz == 1) { if (c1++ == 0) rb1 = p; else rb2 = p; }
        else if (sz == 40) pred = (const int*)p;
        else if (sz == 20) {
            int c = c20++;
            if (c == 0) eA = (const int*)p;
            else if (c == 1) eB = (const int*)p;
            else inc = (const int*)p;
        }
    }
    if (!obs || !act || !ag || !g || !mp_w || !mp_b || !w1 || !b1 || !w2 || !b2 ||
        !w3 || !b3 || !w4 || !b4 || !rw1 || !rb1 || !rw2 || !rb2 || !eA || !eB ||
        !pred || !inc) {
        obs = d_in[0]; act = d_in[1]; ag = d_in[2]; g = d_in[3];
        mp_w = d_in[4]; mp_b = d_in[5]; w1 = d_in[6]; b1 = d_in[7];
        w2 = d_in[8]; b2 = d_in[9]; w3 = d_in[10]; b3 = d_in[11];
        w4 = d_in[12]; b4 = d_in[13]; rw1 = d_in[14]; rb1 = d_in[15];
        rw2 = d_in[16]; rb2 = d_in[17];
        eA = (const int*)d_in[18]; eB = (const int*)d_in[19];
        pred = (const int*)d_in[20]; inc = (const int*)d_in[21];
    }

    float* out = (float*)d_out;
    __bf16* wsW = (__bf16*)d_ws;
    bool use_ws = ws_size >= WS_BYTES + 8;
    int* flags = (int*)((char*)d_ws + WS_BYTES);
    int grid = B / 16;

    if (use_ws) {
        swz<<<(WS_TOTAL + 255) / 256, 256, 0, stream>>>(
            mp_w, w1, w2, w3, w4, wsW, (const unsigned short*)obs, flags);
        gn_main<false><<<grid, 512, 0, stream>>>(
            obs, act, ag, g, mp_b, b1, b2, b3, b4, rw1, rb1, rw2, rb2,
            eA, eB, pred, inc, wsW, mp_w, w1, w2, w3, w4, flags, out, B);
    } else {
        gn_main<true><<<grid, 512, 0, stream>>>(
            obs, act, ag, g, mp_b, b1, b2, b3, b4, rw1, rb1, rw2, rb2,
            eA, eB, pred, inc, wsW, mp_w, w1, w2, w3, w4, flags, out, B);
    }
}

// Round 7
// 184.627 us; speedup vs baseline: 2.1098x; 2.1098x over previous
//
#include <hip/hip_runtime.h>
#include <hip/hip_bf16.h>

typedef __bf16 bf16x8 __attribute__((ext_vector_type(8)));
typedef __bf16 bf16x4 __attribute__((ext_vector_type(4)));
typedef float f32x4 __attribute__((ext_vector_type(4)));

#define MFMA(a, b, c) __builtin_amdgcn_mfma_f32_16x16x32_bf16(a, b, c, 0, 0, 0)

// ws layout (bf16 elem offsets) — weights in MFMA B-fragment order:
// frag[(nt*nKT + kt)*64 + lane][j] = W[kt*32 + (lane>>4)*8 + j][nt*16 + (lane&15)]
constexpr int MP_OFF = 0;
constexpr int W1_OFF = 8192;
constexpr int W2_OFF = 49152;
constexpr int W3_OFF = 114688;
constexpr int W4_OFF = 155648;
constexpr int WS_TOTAL = 221184;
constexpr size_t WS_BYTES = (size_t)WS_TOTAL * 2;

__device__ __forceinline__ float ldf(const void* p, int i, bool f32) {
    return f32 ? ((const float*)p)[i] : (float)(((const __bf16*)p)[i]);
}
__device__ __forceinline__ int geti(const int* p, int i, bool i64) {
    return p[i64 ? 2 * i : i];
}

// Read-side swizzle with fused dtype self-detect (fp32 misread as bf16 shows
// exponent-0xFF halfwords). Block 0 also publishes flags for gn_main.
__global__ void swz(const void* __restrict__ mp, const void* __restrict__ w1,
                    const void* __restrict__ w2, const void* __restrict__ w3,
                    const void* __restrict__ w4, __bf16* __restrict__ ws,
                    const unsigned short* __restrict__ uo, int* __restrict__ flags) {
    __shared__ int s_fw, s_fi;
    int tid = threadIdx.x;
    if (tid == 0) { s_fw = 0; s_fi = 0; }
    __syncthreads();
    const unsigned short* uw = (const unsigned short*)w2;
    int d = 0;
    for (int i = tid; i < 8192; i += 256)
        d |= (((uw[i] >> 7) & 0xFF) == 0xFF) ? 1 : 0;
    if (d) atomicOr(&s_fw, 1);
    if (blockIdx.x == 0) {
        int d0 = 0;
        for (int i = tid; i < 8192; i += 256)
            d0 |= (((uo[i] >> 7) & 0xFF) == 0xFF) ? 1 : 0;
        if (d0) atomicOr(&s_fi, 1);
    }
    __syncthreads();
    bool f32 = s_fw != 0;
    if (blockIdx.x == 0 && tid == 0) { flags[0] = s_fi; flags[1] = s_fw; }

    int idx = blockIdx.x * blockDim.x + tid;
    if (idx >= WS_TOTAL) return;
    const void* src;
    int base, local, nKT, nsh, style, K;
    if (idx < W1_OFF)      { src = mp; base = MP_OFF; local = idx;          nKT = 2; nsh = 7; style = 0; K = 46; }
    else if (idx < W2_OFF) { src = w1; base = W1_OFF; local = idx - W1_OFF; nKT = 5; nsh = 8; style = 1; K = 157; }
    else if (idx < W3_OFF) { src = w2; base = W2_OFF; local = idx - W2_OFF; nKT = 8; nsh = 8; style = 0; K = 256; }
    else if (idx < W4_OFF) { src = w3; base = W3_OFF; local = idx - W3_OFF; nKT = 5; nsh = 8; style = 1; K = 157; }
    else                   { src = w4; base = W4_OFF; local = idx - W4_OFF; nKT = 8; nsh = 8; style = 0; K = 256; }
    int N = 1 << nsh;
    int kp = local >> nsh, n = local & (N - 1);
    int ks = kp;
    bool ok = true;
    if (style == 1) { if (kp >= 32) ks = kp - 3; else if (kp >= 29) ok = false; }
    if (ks >= K) ok = false;
    float v = ok ? ldf(src, ks * N + n, f32) : 0.f;
    int dst = ((n >> 4) * nKT + (kp >> 5)) * 512 +
              (((((kp >> 3) & 3)) << 4) | (n & 15)) * 8 + (kp & 7);
    ws[base + dst] = (__bf16)v;
}

// Direct B-fragment gather fallback (ws too small). Same lane mapping as A-frag.
__device__ __forceinline__ bf16x8 gatherB(const void* W, bool f32, int style,
                                          int K, int N, int k0, int n, int q) {
    bf16x8 r;
#pragma unroll
    for (int j = 0; j < 8; ++j) {
        int k = k0 + q * 8 + j;
        bool ok = true;
        if (style == 1) { if (k >= 32) k -= 3; else if (k >= 29) ok = false; }
        if (k >= K) ok = false;
        float v = ok ? ldf(W, k * N + n, f32) : 0.f;
        r[j] = (__bf16)v;
    }
    return r;
}

// ROUND-1 STRUCTURE (verified clean: FETCH~6.7MB, WRITE~0.13MB, 81us) + T5
// setprio around MFMA clusters. Every 4-blocks/CU restructure (R3/R4/R5)
// produced 100-650MB anomalous scratch/HBM traffic — do not re-attempt
// without ScratchSize/disasm evidence.
// LDS (50,544 B; 512-thr blocks, 8 waves; 3 blocks/CU):
//   s_union[0..8192)   : edge-A frags (PC<=8) — later h frags span [0..12288)
//   s_union[8192..10112): rowbuf 16 x 120 (dead before first h write)
//   s_inp[12800]       : inp frags, 5 mt x 5 kt x 512
template <int PC, int PBASE>
__device__ __forceinline__ void buildA(__bf16* sA, const __bf16* rb, const int* s_esrc,
                                       const int* s_pid0, const int* s_pid1, int tid) {
    for (int i = tid; i < 16 * PC * 8; i += 512) {
        int t = i >> 6, lanep = i & 63;
        int oct = ((t & 1) << 2) | (lanep >> 4);
        int r = (t >> 1) * 16 + (lanep & 15);
        int lb = r / PC, p = PBASE + r % PC;
        const __bf16* row = rb + lb * 120;
        bf16x8 v;
#pragma unroll
        for (int j = 0; j < 8; ++j) {
            int k = oct * 8 + j;
            __bf16 x = (__bf16)0.f;
            if (k < 10) x = row[k];
            else if (k < 14) x = row[85 + (k - 10)];
            else if (k < 16) x = row[89 + ((k == 14) ? s_pid0[p] : s_pid1[p])];
            else if (k < 31) x = row[10 + s_esrc[p] * 15 + (k - 16)];
            else if (k < 46) x = row[10 + (p >> 2) * 15 + (k - 31)];
            v[j] = x;
        }
        *(bf16x8*)(sA + t * 512 + lanep * 8) = v;
    }
}

// stage1: A=edges, B=mp_w frags; 8 waves x 1 nt; bw hoisted, flat m loop.
// setprio(1) across the MFMA-dense m-loop (T5: helps when co-resident blocks
// are at different phases; 3 independent blocks/CU here).
template <int PC, int PBASE, bool DW>
__device__ __forceinline__ void stage1(const __bf16* Wf, const void* Wn, bool fW,
                                       const void* mp_b, const __bf16* sA,
                                       __bf16* s_inp, int wave, int lane) {
    int q = lane >> 4, c = lane & 15;
    int nt = wave;
    float mb = ldf(mp_b, nt * 16 + c, fW);
    bf16x8 bw[2];
#pragma unroll
    for (int kt = 0; kt < 2; ++kt) {
        if constexpr (DW) bw[kt] = gatherB(Wn, fW, 0, 46, 128, kt * 32, nt * 16 + c, q);
        else bw[kt] = *(const bf16x8*)(Wf + (nt * 2 + kt) * 512 + lane * 8);
    }
    f32x4 zero4 = {0.f, 0.f, 0.f, 0.f};
    __builtin_amdgcn_s_setprio(1);
#pragma unroll
    for (int m = 0; m < PC; ++m) {
        f32x4 acc = zero4;
#pragma unroll
        for (int kt = 0; kt < 2; ++kt) {
            bf16x8 a = *(const bf16x8*)(sA + (m * 2 + kt) * 512 + lane * 8);
            acc = MFMA(a, bw[kt], acc);
        }
        float sum = 0.f;
#pragma unroll
        for (int rr = 0; rr < 4; ++rr) {
            float z = acc[rr] + mb;
            sum += (z > 0.f) ? z : 0.f;
        }
        int r0 = m * 16 + q * 4;          // PC in {8,4}: pow2 div/mod, groups of 4 intact
        int lb = r0 / PC;
        int o = (PBASE + r0 % PC) >> 2;
        int rinp = lb * 5 + o;
        int kk = 32 + nt * 16 + c;
        s_inp[((rinp >> 4) * 5 + (kk >> 5)) * 512 +
              ((((kk & 31) >> 3) << 4) + (rinp & 15)) * 8 + (kk & 7)] = (__bf16)sum;
    }
    __builtin_amdgcn_s_setprio(0);
}

// stage2 SWAPPED: D'[hcol][row] = MFMA(A=W1-frag, B=inp-frag); kt outer so each
// inp b-frag is read ONCE (shared across both n).
template <int MTN, bool DW>
__device__ __forceinline__ void stage2s(int mbase, const __bf16* Wf, const void* Wn,
                                        bool fW, const void* Ba, __bf16* s_h,
                                        const __bf16* s_inp, int wave, int lane) {
    int q = lane >> 4, c = lane & 15;
    f32x4 zero4 = {0.f, 0.f, 0.f, 0.f};
    f32x4 acc[2][MTN];
#pragma unroll
    for (int n = 0; n < 2; ++n)
#pragma unroll
        for (int m = 0; m < MTN; ++m) acc[n][m] = zero4;
    __builtin_amdgcn_s_setprio(1);
#pragma unroll
    for (int kt = 0; kt < 5; ++kt) {
        bf16x8 b[MTN];
#pragma unroll
        for (int m = 0; m < MTN; ++m)
            b[m] = *(const bf16x8*)(s_inp + ((mbase + m) * 5 + kt) * 512 + lane * 8);
#pragma unroll
        for (int n = 0; n < 2; ++n) {
            int ht = wave * 2 + n;
            bf16x8 aw;
            if constexpr (DW) aw = gatherB(Wn, fW, 1, 157, 256, kt * 32, ht * 16 + c, q);
            else aw = *(const bf16x8*)(Wf + (ht * 5 + kt) * 512 + lane * 8);
#pragma unroll
            for (int m = 0; m < MTN; ++m) acc[n][m] = MFMA(aw, b[m], acc[n][m]);
        }
    }
    __builtin_amdgcn_s_setprio(0);
    float bias_r[2][4];
#pragma unroll
    for (int n = 0; n < 2; ++n)
#pragma unroll
        for (int rg = 0; rg < 4; ++rg)
            bias_r[n][rg] = ldf(Ba, (wave * 2 + n) * 16 + q * 4 + rg, fW);
#pragma unroll
    for (int n = 0; n < 2; ++n) {
        int ht = wave * 2 + n;
#pragma unroll
        for (int m = 0; m < MTN; ++m) {
            bf16x4 hv;
#pragma unroll
            for (int rg = 0; rg < 4; ++rg) {
                float z = acc[n][m][rg] + bias_r[n][rg];
                hv[rg] = (__bf16)((z > 0.f) ? z : 0.f);
            }
            *(bf16x4*)(s_h + (m * 8 + (ht >> 1)) * 512 +
                       ((((ht & 1) * 2 + (q >> 1)) << 4) | c) * 8 + ((q & 1) << 2)) = hv;
        }
    }
}

// stage3 SWAPPED: D'[ncol][row] = MFMA(A=W2-frag, B=h-frag); kt outer, h b-frags
// read once per kt (shared across both n).
template <int MTN, bool DW>
__device__ __forceinline__ void stage3s(int mbase, const __bf16* Wf, const void* Wn,
                                        bool fW, const void* Bb, const void* Rh,
                                        const __bf16* s_h, float* s_qp, int wave, int lane) {
    int q = lane >> 4, c = lane & 15;
    f32x4 zero4 = {0.f, 0.f, 0.f, 0.f};
    f32x4 acc[2][MTN];
#pragma unroll
    for (int n = 0; n < 2; ++n)
#pragma unroll
        for (int m = 0; m < MTN; ++m) acc[n][m] = zero4;
    __builtin_amdgcn_s_setprio(1);
#pragma unroll
    for (int kt = 0; kt < 8; ++kt) {
        bf16x8 b[MTN];
#pragma unroll
        for (int m = 0; m < MTN; ++m)
            b[m] = *(const bf16x8*)(s_h + (m * 8 + kt) * 512 + lane * 8);
#pragma unroll
        for (int n = 0; n < 2; ++n) {
            int nt = wave * 2 + n;
            bf16x8 aw;
            if constexpr (DW) aw = gatherB(Wn, fW, 0, 256, 256, kt * 32, nt * 16 + c, q);
            else aw = *(const bf16x8*)(Wf + (nt * 8 + kt) * 512 + lane * 8);
#pragma unroll
            for (int m = 0; m < MTN; ++m) acc[n][m] = MFMA(aw, b[m], acc[n][m]);
        }
    }
    __builtin_amdgcn_s_setprio(0);
    float bias_r[2][4], rho_r[2][4];
#pragma unroll
    for (int n = 0; n < 2; ++n)
#pragma unroll
        for (int rg = 0; rg < 4; ++rg) {
            int ncol = (wave * 2 + n) * 16 + q * 4 + rg;
            bias_r[n][rg] = ldf(Bb, ncol, fW);
            rho_r[n][rg] = ldf(Rh, ncol, fW);
        }
    float rowsum[MTN];
#pragma unroll
    for (int m = 0; m < MTN; ++m) rowsum[m] = 0.f;
#pragma unroll
    for (int n = 0; n < 2; ++n)
#pragma unroll
        for (int m = 0; m < MTN; ++m)
#pragma unroll
            for (int rg = 0; rg < 4; ++rg) {
                float z = acc[n][m][rg] + bias_r[n][rg];
                z = (z > 0.f) ? z : 0.f;
                rowsum[m] += z * rho_r[n][rg];
            }
#pragma unroll
    for (int m = 0; m < MTN; ++m) {
        float v = rowsum[m];
        v += __shfl_xor(v, 16);
        v += __shfl_xor(v, 32);
        if (q == 0) {
            int r0 = (mbase + m) * 16 + c;  // rinp = b*5+o
            atomicAdd(&s_qp[r0 / 5], v);
        }
    }
}

template <bool DW>
__global__ __launch_bounds__(512, 6) void gn_main(
    const void* __restrict__ obs, const void* __restrict__ act,
    const void* __restrict__ ag, const void* __restrict__ g,
    const void* __restrict__ mp_b, const void* __restrict__ b1,
    const void* __restrict__ b2, const void* __restrict__ b3,
    const void* __restrict__ b4, const void* __restrict__ rw1,
    const void* __restrict__ rb1, const void* __restrict__ rw2,
    const void* __restrict__ rb2, const int* __restrict__ eA,
    const int* __restrict__ eB, const int* __restrict__ pred_ids,
    const int* __restrict__ incoming, const __bf16* __restrict__ wsW,
    const void* __restrict__ mp_w, const void* __restrict__ w1,
    const void* __restrict__ w2, const void* __restrict__ w3,
    const void* __restrict__ w4, const int* __restrict__ flags,
    float* __restrict__ out, int Btot) {
    __shared__ __align__(16) __bf16 s_union[12288];
    __shared__ __align__(16) __bf16 s_inp[12800];
    __shared__ __align__(16) float s_q[32];
    __shared__ int s_esrc[20], s_pid0[20], s_pid1[20];

    int tid = threadIdx.x, lane = tid & 63, wave = tid >> 6;
    __bf16* rb = s_union + 8192;  // [8192,10112): outside buildA region; dead before h
    int b0 = blockIdx.x * 16;

    // ---- dtype flags ----
    bool fI, fW;
    if constexpr (DW) {
        const unsigned short* uo = (const unsigned short*)obs;
        const unsigned short* uw = (const unsigned short*)w2;
        int d0 = 0, d1 = 0;
        for (int i = lane; i < 8192; i += 64) {
            if (((uo[i] >> 7) & 0xFF) == 0xFF) d0 = 1;
            if (((uw[i] >> 7) & 0xFF) == 0xFF) d1 = 1;
        }
        fI = __ballot(d0) != 0;
        fW = __ballot(d1) != 0;
    } else {
        fI = flags[0] != 0;
        fW = flags[1] != 0;
    }

    // ---- int width + src/dst disambiguation ----
    bool i64_i = (incoming[1] == 0);
    bool i64_p = (pred_ids[1] == 0);
    bool i64_e = (eA[9] == 0);
    const int* es = (geti(eA, 4, i64_e) == 1) ? eA : eB;

    if (tid < 20) {
        int e = geti(incoming, tid, i64_i);  // tid = o*4+j; edge p=tid has dst o=tid/4
        s_esrc[tid] = geti(es, e, i64_e);
        s_pid0[tid] = geti(pred_ids, 2 * e, i64_p);
        s_pid1[tid] = geti(pred_ids, 2 * e + 1, i64_p);
    }

    for (int i = tid; i < 16 * 120; i += 512) {
        int lb = i / 120, cidx = i % 120;
        int bg = b0 + lb;
        float v = 0.f;
        if (cidx < 85) v = ldf(obs, bg * 85 + cidx, fI);
        else if (cidx < 89) v = ldf(act, bg * 4 + (cidx - 85), fI);
        else if (cidx < 119) {
            int t = cidx - 89;
            v = ldf(g, bg * 30 + t, fI) - ldf(ag, bg * 30 + t, fI);
        }
        rb[i] = (__bf16)v;
    }
    __syncthreads();

    // inp kt=0 plane (k<32), conflict-free mapping (lanep = i&63)
    for (int i = tid; i < 320; i += 512) {
        int mt = i >> 6, lanep = i & 63;
        int oct = lanep >> 4;
        int r = mt * 16 + (lanep & 15);
        int lb = r / 5, o = r % 5;
        const __bf16* row = rb + lb * 120;
        bf16x8 v;
#pragma unroll
        for (int j = 0; j < 8; ++j) {
            int k = oct * 8 + j;
            __bf16 x = (__bf16)0.f;
            if (k < 4) x = row[85 + k];
            else if (k < 14) x = row[k - 4];
            else if (k < 29) x = row[10 + o * 15 + (k - 14)];
            v[j] = x;
        }
        *(bf16x8*)(s_inp + mt * 2560 + lanep * 8) = v;
    }
    buildA<8, 0>(s_union, rb, s_esrc, s_pid0, s_pid1, tid);
    __syncthreads();
    stage1<8, 0, DW>(wsW + MP_OFF, mp_w, fW, mp_b, s_union, s_inp, wave, lane);
    __syncthreads();
    buildA<8, 8>(s_union, rb, s_esrc, s_pid0, s_pid1, tid);
    __syncthreads();
    stage1<8, 8, DW>(wsW + MP_OFF, mp_w, fW, mp_b, s_union, s_inp, wave, lane);
    __syncthreads();
    buildA<4, 16>(s_union, rb, s_esrc, s_pid0, s_pid1, tid);
    __syncthreads();
    stage1<4, 16, DW>(wsW + MP_OFF, mp_w, fW, mp_b, s_union, s_inp, wave, lane);
    if (tid < 32) s_q[tid] = 0.f;
    __syncthreads();

    for (int P = 0; P < 2; ++P) {
        const __bf16* Wa = wsW + (P ? W3_OFF : W1_OFF);
        const __bf16* Wb = wsW + (P ? W4_OFF : W2_OFF);
        const void* Wan = P ? w3 : w1;
        const void* Wbn = P ? w4 : w2;
        const void* ba = P ? b3 : b1;
        const void* bb = P ? b4 : b2;
        const void* rho = P ? rw2 : rw1;
        float* qp = s_q + P * 16;
        stage2s<3, DW>(0, Wa, Wan, fW, ba, s_union, s_inp, wave, lane);
        __syncthreads();
        stage3s<3, DW>(0, Wb, Wbn, fW, bb, rho, s_union, qp, wave, lane);
        __syncthreads();
        stage2s<2, DW>(3, Wa, Wan, fW, ba, s_union, s_inp, wave, lane);
        __syncthreads();
        stage3s<2, DW>(3, Wb, Wbn, fW, bb, rho, s_union, qp, wave, lane);
        __syncthreads();
    }

    if (tid < 16) {
        out[b0 + tid] = s_q[tid] + ldf(rb1, 0, fW);
        out[Btot + b0 + tid] = s_q[16 + tid] + ldf(rb2, 0, fW);
    }
}

extern "C" void kernel_launch(void* const* d_in, const int* in_sizes, int n_in,
                              void* d_out, int out_size, void* d_ws, size_t ws_size,
                              hipStream_t stream) {
    int B = out_size / 2;  // 16384

    const void *obs = nullptr, *act = nullptr, *ag = nullptr, *g = nullptr;
    const void *mp_w = nullptr, *mp_b = nullptr;
    const void *w1 = nullptr, *b1 = nullptr, *w2 = nullptr, *b2 = nullptr;
    const void *w3 = nullptr, *b3 = nullptr, *w4 = nullptr, *b4 = nullptr;
    const void *rw1 = nullptr, *rb1 = nullptr, *rw2 = nullptr, *rb2 = nullptr;
    const int *eA = nullptr, *eB = nullptr, *pred = nullptr, *inc = nullptr;
    int c30 = 0, c256 = 0, c1 = 0, c40k = 0, c65k = 0, c20 = 0;
    for (int i = 0; i < n_in; ++i) {
        int sz = in_sizes[i];
        const void* p = d_in[i];
        if (sz == B * 85) obs = p;
        else if (sz == B * 30) { if (c30++ == 0) ag = p; else g = p; }
        else if (sz == 5888) mp_w = p;
        else if (sz == 128) mp_b = p;
        else if (sz == 40192) { if (c40k++ == 0) w1 = p; else w3 = p; }
        else if (sz == 65536 || sz == B * 4) {
            int c = c65k++;
            if (c == 0) act = p; else if (c == 1) w2 = p; else w4 = p;
        }
        else if (sz == 256) {
            int c = c256++;
            if (c == 0) b1 = p; else if (c == 1) b2 = p; else if (c == 2) b3 = p;
            else if (c == 3) b4 = p; else if (c == 4) rw1 = p; else rw2 = p;
        }
        else if (sz == 1) { if (c1++ == 0) rb1 = p; else rb2 = p; }
        else if (sz == 40) pred = (const int*)p;
        else if (sz == 20) {
            int c = c20++;
            if (c == 0) eA = (const int*)p;
            else if (c == 1) eB = (const int*)p;
            else inc = (const int*)p;
        }
    }
    if (!obs || !act || !ag || !g || !mp_w || !mp_b || !w1 || !b1 || !w2 || !b2 ||
        !w3 || !b3 || !w4 || !b4 || !rw1 || !rb1 || !rw2 || !rb2 || !eA || !eB ||
        !pred || !inc) {
        obs = d_in[0]; act = d_in[1]; ag = d_in[2]; g = d_in[3];
        mp_w = d_in[4]; mp_b = d_in[5]; w1 = d_in[6]; b1 = d_in[7];
        w2 = d_in[8]; b2 = d_in[9]; w3 = d_in[10]; b3 = d_in[11];
        w4 = d_in[12]; b4 = d_in[13]; rw1 = d_in[14]; rb1 = d_in[15];
        rw2 = d_in[16]; rb2 = d_in[17];
        eA = (const int*)d_in[18]; eB = (const int*)d_in[19];
        pred = (const int*)d_in[20]; inc = (const int*)d_in[21];
    }

    float* out = (float*)d_out;
    __bf16* wsW = (__bf16*)d_ws;
    bool use_ws = ws_size >= WS_BYTES + 8;
    int* flags = (int*)((char*)d_ws + WS_BYTES);
    int grid = B / 16;

    if (use_ws) {
        swz<<<(WS_TOTAL + 255) / 256, 256, 0, stream>>>(
            mp_w, w1, w2, w3, w4, wsW, (const unsigned short*)obs, flags);
        gn_main<false><<<grid, 512, 0, stream>>>(
            obs, act, ag, g, mp_b, b1, b2, b3, b4, rw1, rb1, rw2, rb2,
            eA, eB, pred, inc, wsW, mp_w, w1, w2, w3, w4, flags, out, B);
    } else {
        gn_main<true><<<grid, 512, 0, stream>>>(
            obs, act, ag, g, mp_b, b1, b2, b3, b4, rw1, rb1, rw2, rb2,
            eA, eB, pred, inc, wsW, mp_w, w1, w2, w3, w4, flags, out, B);
    }
}

// Round 8
// 178.556 us; speedup vs baseline: 2.1815x; 1.0340x over previous
//
#include <hip/hip_runtime.h>
#include <hip/hip_bf16.h>

typedef __bf16 bf16x8 __attribute__((ext_vector_type(8)));
typedef __bf16 bf16x4 __attribute__((ext_vector_type(4)));
typedef float f32x4 __attribute__((ext_vector_type(4)));

#define MFMA(a, b, c) __builtin_amdgcn_mfma_f32_16x16x32_bf16(a, b, c, 0, 0, 0)

// ws layout (bf16 elem offsets) — weights in MFMA B-fragment order:
// frag[(nt*nKT + kt)*64 + lane][j] = W[kt*32 + (lane>>4)*8 + j][nt*16 + (lane&15)]
constexpr int MP_OFF = 0;
constexpr int W1_OFF = 8192;
constexpr int W2_OFF = 49152;
constexpr int W3_OFF = 114688;
constexpr int W4_OFF = 155648;
constexpr int WS_TOTAL = 221184;
constexpr size_t WS_BYTES = (size_t)WS_TOTAL * 2;

__device__ __forceinline__ float ldf(const void* p, int i, bool f32) {
    return f32 ? ((const float*)p)[i] : (float)(((const __bf16*)p)[i]);
}
__device__ __forceinline__ int geti(const int* p, int i, bool i64) {
    return p[i64 ? 2 * i : i];
}

// Read-side swizzle with fused dtype self-detect (fp32 misread as bf16 shows
// exponent-0xFF halfwords). Block 0 also publishes flags for gn_main.
__global__ void swz(const void* __restrict__ mp, const void* __restrict__ w1,
                    const void* __restrict__ w2, const void* __restrict__ w3,
                    const void* __restrict__ w4, __bf16* __restrict__ ws,
                    const unsigned short* __restrict__ uo, int* __restrict__ flags) {
    __shared__ int s_fw, s_fi;
    int tid = threadIdx.x;
    if (tid == 0) { s_fw = 0; s_fi = 0; }
    __syncthreads();
    const unsigned short* uw = (const unsigned short*)w2;
    int d = 0;
    for (int i = tid; i < 8192; i += 256)
        d |= (((uw[i] >> 7) & 0xFF) == 0xFF) ? 1 : 0;
    if (d) atomicOr(&s_fw, 1);
    if (blockIdx.x == 0) {
        int d0 = 0;
        for (int i = tid; i < 8192; i += 256)
            d0 |= (((uo[i] >> 7) & 0xFF) == 0xFF) ? 1 : 0;
        if (d0) atomicOr(&s_fi, 1);
    }
    __syncthreads();
    bool f32 = s_fw != 0;
    if (blockIdx.x == 0 && tid == 0) { flags[0] = s_fi; flags[1] = s_fw; }

    int idx = blockIdx.x * blockDim.x + tid;
    if (idx >= WS_TOTAL) return;
    const void* src;
    int base, local, nKT, nsh, style, K;
    if (idx < W1_OFF)      { src = mp; base = MP_OFF; local = idx;          nKT = 2; nsh = 7; style = 0; K = 46; }
    else if (idx < W2_OFF) { src = w1; base = W1_OFF; local = idx - W1_OFF; nKT = 5; nsh = 8; style = 1; K = 157; }
    else if (idx < W3_OFF) { src = w2; base = W2_OFF; local = idx - W2_OFF; nKT = 8; nsh = 8; style = 0; K = 256; }
    else if (idx < W4_OFF) { src = w3; base = W3_OFF; local = idx - W3_OFF; nKT = 5; nsh = 8; style = 1; K = 157; }
    else                   { src = w4; base = W4_OFF; local = idx - W4_OFF; nKT = 8; nsh = 8; style = 0; K = 256; }
    int N = 1 << nsh;
    int kp = local >> nsh, n = local & (N - 1);
    int ks = kp;
    bool ok = true;
    if (style == 1) { if (kp >= 32) ks = kp - 3; else if (kp >= 29) ok = false; }
    if (ks >= K) ok = false;
    float v = ok ? ldf(src, ks * N + n, f32) : 0.f;
    int dst = ((n >> 4) * nKT + (kp >> 5)) * 512 +
              (((((kp >> 3) & 3)) << 4) | (n & 15)) * 8 + (kp & 7);
    ws[base + dst] = (__bf16)v;
}

// Direct B-fragment gather fallback (ws too small). Same lane mapping as A-frag.
__device__ __forceinline__ bf16x8 gatherB(const void* W, bool f32, int style,
                                          int K, int N, int k0, int n, int q) {
    bf16x8 r;
#pragma unroll
    for (int j = 0; j < 8; ++j) {
        int k = k0 + q * 8 + j;
        bool ok = true;
        if (style == 1) { if (k >= 32) k -= 3; else if (k >= 29) ok = false; }
        if (k >= K) ok = false;
        float v = ok ? ldf(W, k * N + n, f32) : 0.f;
        r[j] = (__bf16)v;
    }
    return r;
}

// ROUND-1 STRUCTURE — the measured optimum of this session.
// Verified clean counters: FETCH~6.7MB, WRITE~0.13MB, VGPR 40, ~81us.
// Negative results (do NOT reintroduce without new evidence):
//   * s_setprio around MFMA clusters: −10% (R7; starves co-resident blocks'
//     staging phases — all 8 waves are barrier-lockstep here, no role split).
//   * Any 4-blocks/CU restructure (R3/R4/R5): 100-650MB anomalous scratch
//     traffic regardless of launch bounds; needs ScratchSize/disasm to chase.
//   * Global-scratch s_inp (R2): spills through L2 to HBM, 2.3TB/s-bound.
// LDS (50,544 B; 512-thr blocks, 8 waves; 3 blocks/CU):
//   s_union[0..8192)   : edge-A frags (PC<=8) — later h frags span [0..12288)
//   s_union[8192..10112): rowbuf 16 x 120 (dead before first h write)
//   s_inp[12800]       : inp frags, 5 mt x 5 kt x 512
template <int PC, int PBASE>
__device__ __forceinline__ void buildA(__bf16* sA, const __bf16* rb, const int* s_esrc,
                                       const int* s_pid0, const int* s_pid1, int tid) {
    for (int i = tid; i < 16 * PC * 8; i += 512) {
        int t = i >> 6, lanep = i & 63;
        int oct = ((t & 1) << 2) | (lanep >> 4);
        int r = (t >> 1) * 16 + (lanep & 15);
        int lb = r / PC, p = PBASE + r % PC;
        const __bf16* row = rb + lb * 120;
        bf16x8 v;
#pragma unroll
        for (int j = 0; j < 8; ++j) {
            int k = oct * 8 + j;
            __bf16 x = (__bf16)0.f;
            if (k < 10) x = row[k];
            else if (k < 14) x = row[85 + (k - 10)];
            else if (k < 16) x = row[89 + ((k == 14) ? s_pid0[p] : s_pid1[p])];
            else if (k < 31) x = row[10 + s_esrc[p] * 15 + (k - 16)];
            else if (k < 46) x = row[10 + (p >> 2) * 15 + (k - 31)];
            v[j] = x;
        }
        *(bf16x8*)(sA + t * 512 + lanep * 8) = v;
    }
}

// stage1: A=edges, B=mp_w frags; 8 waves x 1 nt; bw hoisted, flat m loop.
template <int PC, int PBASE, bool DW>
__device__ __forceinline__ void stage1(const __bf16* Wf, const void* Wn, bool fW,
                                       const void* mp_b, const __bf16* sA,
                                       __bf16* s_inp, int wave, int lane) {
    int q = lane >> 4, c = lane & 15;
    int nt = wave;
    float mb = ldf(mp_b, nt * 16 + c, fW);
    bf16x8 bw[2];
#pragma unroll
    for (int kt = 0; kt < 2; ++kt) {
        if constexpr (DW) bw[kt] = gatherB(Wn, fW, 0, 46, 128, kt * 32, nt * 16 + c, q);
        else bw[kt] = *(const bf16x8*)(Wf + (nt * 2 + kt) * 512 + lane * 8);
    }
    f32x4 zero4 = {0.f, 0.f, 0.f, 0.f};
#pragma unroll
    for (int m = 0; m < PC; ++m) {
        f32x4 acc = zero4;
#pragma unroll
        for (int kt = 0; kt < 2; ++kt) {
            bf16x8 a = *(const bf16x8*)(sA + (m * 2 + kt) * 512 + lane * 8);
            acc = MFMA(a, bw[kt], acc);
        }
        float sum = 0.f;
#pragma unroll
        for (int rr = 0; rr < 4; ++rr) {
            float z = acc[rr] + mb;
            sum += (z > 0.f) ? z : 0.f;
        }
        int r0 = m * 16 + q * 4;          // PC in {8,4}: pow2 div/mod, groups of 4 intact
        int lb = r0 / PC;
        int o = (PBASE + r0 % PC) >> 2;
        int rinp = lb * 5 + o;
        int kk = 32 + nt * 16 + c;
        s_inp[((rinp >> 4) * 5 + (kk >> 5)) * 512 +
              ((((kk & 31) >> 3) << 4) + (rinp & 15)) * 8 + (kk & 7)] = (__bf16)sum;
    }
}

// stage2 SWAPPED: D'[hcol][row] = MFMA(A=W1-frag, B=inp-frag); kt outer so each
// inp b-frag is read ONCE (shared across both n).
template <int MTN, bool DW>
__device__ __forceinline__ void stage2s(int mbase, const __bf16* Wf, const void* Wn,
                                        bool fW, const void* Ba, __bf16* s_h,
                                        const __bf16* s_inp, int wave, int lane) {
    int q = lane >> 4, c = lane & 15;
    f32x4 zero4 = {0.f, 0.f, 0.f, 0.f};
    f32x4 acc[2][MTN];
#pragma unroll
    for (int n = 0; n < 2; ++n)
#pragma unroll
        for (int m = 0; m < MTN; ++m) acc[n][m] = zero4;
#pragma unroll
    for (int kt = 0; kt < 5; ++kt) {
        bf16x8 b[MTN];
#pragma unroll
        for (int m = 0; m < MTN; ++m)
            b[m] = *(const bf16x8*)(s_inp + ((mbase + m) * 5 + kt) * 512 + lane * 8);
#pragma unroll
        for (int n = 0; n < 2; ++n) {
            int ht = wave * 2 + n;
            bf16x8 aw;
            if constexpr (DW) aw = gatherB(Wn, fW, 1, 157, 256, kt * 32, ht * 16 + c, q);
            else aw = *(const bf16x8*)(Wf + (ht * 5 + kt) * 512 + lane * 8);
#pragma unroll
            for (int m = 0; m < MTN; ++m) acc[n][m] = MFMA(aw, b[m], acc[n][m]);
        }
    }
    float bias_r[2][4];
#pragma unroll
    for (int n = 0; n < 2; ++n)
#pragma unroll
        for (int rg = 0; rg < 4; ++rg)
            bias_r[n][rg] = ldf(Ba, (wave * 2 + n) * 16 + q * 4 + rg, fW);
#pragma unroll
    for (int n = 0; n < 2; ++n) {
        int ht = wave * 2 + n;
#pragma unroll
        for (int m = 0; m < MTN; ++m) {
            bf16x4 hv;
#pragma unroll
            for (int rg = 0; rg < 4; ++rg) {
                float z = acc[n][m][rg] + bias_r[n][rg];
                hv[rg] = (__bf16)((z > 0.f) ? z : 0.f);
            }
            *(bf16x4*)(s_h + (m * 8 + (ht >> 1)) * 512 +
                       ((((ht & 1) * 2 + (q >> 1)) << 4) | c) * 8 + ((q & 1) << 2)) = hv;
        }
    }
}

// stage3 SWAPPED: D'[ncol][row] = MFMA(A=W2-frag, B=h-frag); kt outer, h b-frags
// read once per kt (shared across both n).
template <int MTN, bool DW>
__device__ __forceinline__ void stage3s(int mbase, const __bf16* Wf, const void* Wn,
                                        bool fW, const void* Bb, const void* Rh,
                                        const __bf16* s_h, float* s_qp, int wave, int lane) {
    int q = lane >> 4, c = lane & 15;
    f32x4 zero4 = {0.f, 0.f, 0.f, 0.f};
    f32x4 acc[2][MTN];
#pragma unroll
    for (int n = 0; n < 2; ++n)
#pragma unroll
        for (int m = 0; m < MTN; ++m) acc[n][m] = zero4;
#pragma unroll
    for (int kt = 0; kt < 8; ++kt) {
        bf16x8 b[MTN];
#pragma unroll
        for (int m = 0; m < MTN; ++m)
            b[m] = *(const bf16x8*)(s_h + (m * 8 + kt) * 512 + lane * 8);
#pragma unroll
        for (int n = 0; n < 2; ++n) {
            int nt = wave * 2 + n;
            bf16x8 aw;
            if constexpr (DW) aw = gatherB(Wn, fW, 0, 256, 256, kt * 32, nt * 16 + c, q);
            else aw = *(const bf16x8*)(Wf + (nt * 8 + kt) * 512 + lane * 8);
#pragma unroll
            for (int m = 0; m < MTN; ++m) acc[n][m] = MFMA(aw, b[m], acc[n][m]);
        }
    }
    float bias_r[2][4], rho_r[2][4];
#pragma unroll
    for (int n = 0; n < 2; ++n)
#pragma unroll
        for (int rg = 0; rg < 4; ++rg) {
            int ncol = (wave * 2 + n) * 16 + q * 4 + rg;
            bias_r[n][rg] = ldf(Bb, ncol, fW);
            rho_r[n][rg] = ldf(Rh, ncol, fW);
        }
    float rowsum[MTN];
#pragma unroll
    for (int m = 0; m < MTN; ++m) rowsum[m] = 0.f;
#pragma unroll
    for (int n = 0; n < 2; ++n)
#pragma unroll
        for (int m = 0; m < MTN; ++m)
#pragma unroll
            for (int rg = 0; rg < 4; ++rg) {
                float z = acc[n][m][rg] + bias_r[n][rg];
                z = (z > 0.f) ? z : 0.f;
                rowsum[m] += z * rho_r[n][rg];
            }
#pragma unroll
    for (int m = 0; m < MTN; ++m) {
        float v = rowsum[m];
        v += __shfl_xor(v, 16);
        v += __shfl_xor(v, 32);
        if (q == 0) {
            int r0 = (mbase + m) * 16 + c;  // rinp = b*5+o
            atomicAdd(&s_qp[r0 / 5], v);
        }
    }
}

template <bool DW>
__global__ __launch_bounds__(512, 6) void gn_main(
    const void* __restrict__ obs, const void* __restrict__ act,
    const void* __restrict__ ag, const void* __restrict__ g,
    const void* __restrict__ mp_b, const void* __restrict__ b1,
    const void* __restrict__ b2, const void* __restrict__ b3,
    const void* __restrict__ b4, const void* __restrict__ rw1,
    const void* __restrict__ rb1, const void* __restrict__ rw2,
    const void* __restrict__ rb2, const int* __restrict__ eA,
    const int* __restrict__ eB, const int* __restrict__ pred_ids,
    const int* __restrict__ incoming, const __bf16* __restrict__ wsW,
    const void* __restrict__ mp_w, const void* __restrict__ w1,
    const void* __restrict__ w2, const void* __restrict__ w3,
    const void* __restrict__ w4, const int* __restrict__ flags,
    float* __restrict__ out, int Btot) {
    __shared__ __align__(16) __bf16 s_union[12288];
    __shared__ __align__(16) __bf16 s_inp[12800];
    __shared__ __align__(16) float s_q[32];
    __shared__ int s_esrc[20], s_pid0[20], s_pid1[20];

    int tid = threadIdx.x, lane = tid & 63, wave = tid >> 6;
    __bf16* rb = s_union + 8192;  // [8192,10112): outside buildA region; dead before h
    int b0 = blockIdx.x * 16;

    // ---- dtype flags ----
    bool fI, fW;
    if constexpr (DW) {
        const unsigned short* uo = (const unsigned short*)obs;
        const unsigned short* uw = (const unsigned short*)w2;
        int d0 = 0, d1 = 0;
        for (int i = lane; i < 8192; i += 64) {
            if (((uo[i] >> 7) & 0xFF) == 0xFF) d0 = 1;
            if (((uw[i] >> 7) & 0xFF) == 0xFF) d1 = 1;
        }
        fI = __ballot(d0) != 0;
        fW = __ballot(d1) != 0;
    } else {
        fI = flags[0] != 0;
        fW = flags[1] != 0;
    }

    // ---- int width + src/dst disambiguation ----
    bool i64_i = (incoming[1] == 0);
    bool i64_p = (pred_ids[1] == 0);
    bool i64_e = (eA[9] == 0);
    const int* es = (geti(eA, 4, i64_e) == 1) ? eA : eB;

    if (tid < 20) {
        int e = geti(incoming, tid, i64_i);  // tid = o*4+j; edge p=tid has dst o=tid/4
        s_esrc[tid] = geti(es, e, i64_e);
        s_pid0[tid] = geti(pred_ids, 2 * e, i64_p);
        s_pid1[tid] = geti(pred_ids, 2 * e + 1, i64_p);
    }

    for (int i = tid; i < 16 * 120; i += 512) {
        int lb = i / 120, cidx = i % 120;
        int bg = b0 + lb;
        float v = 0.f;
        if (cidx < 85) v = ldf(obs, bg * 85 + cidx, fI);
        else if (cidx < 89) v = ldf(act, bg * 4 + (cidx - 85), fI);
        else if (cidx < 119) {
            int t = cidx - 89;
            v = ldf(g, bg * 30 + t, fI) - ldf(ag, bg * 30 + t, fI);
        }
        rb[i] = (__bf16)v;
    }
    __syncthreads();

    // inp kt=0 plane (k<32), conflict-free mapping (lanep = i&63)
    for (int i = tid; i < 320; i += 512) {
        int mt = i >> 6, lanep = i & 63;
        int oct = lanep >> 4;
        int r = mt * 16 + (lanep & 15);
        int lb = r / 5, o = r % 5;
        const __bf16* row = rb + lb * 120;
        bf16x8 v;
#pragma unroll
        for (int j = 0; j < 8; ++j) {
            int k = oct * 8 + j;
            __bf16 x = (__bf16)0.f;
            if (k < 4) x = row[85 + k];
            else if (k < 14) x = row[k - 4];
            else if (k < 29) x = row[10 + o * 15 + (k - 14)];
            v[j] = x;
        }
        *(bf16x8*)(s_inp + mt * 2560 + lanep * 8) = v;
    }
    buildA<8, 0>(s_union, rb, s_esrc, s_pid0, s_pid1, tid);
    __syncthreads();
    stage1<8, 0, DW>(wsW + MP_OFF, mp_w, fW, mp_b, s_union, s_inp, wave, lane);
    __syncthreads();
    buildA<8, 8>(s_union, rb, s_esrc, s_pid0, s_pid1, tid);
    __syncthreads();
    stage1<8, 8, DW>(wsW + MP_OFF, mp_w, fW, mp_b, s_union, s_inp, wave, lane);
    __syncthreads();
    buildA<4, 16>(s_union, rb, s_esrc, s_pid0, s_pid1, tid);
    __syncthreads();
    stage1<4, 16, DW>(wsW + MP_OFF, mp_w, fW, mp_b, s_union, s_inp, wave, lane);
    if (tid < 32) s_q[tid] = 0.f;
    __syncthreads();

    for (int P = 0; P < 2; ++P) {
        const __bf16* Wa = wsW + (P ? W3_OFF : W1_OFF);
        const __bf16* Wb = wsW + (P ? W4_OFF : W2_OFF);
        const void* Wan = P ? w3 : w1;
        const void* Wbn = P ? w4 : w2;
        const void* ba = P ? b3 : b1;
        const void* bb = P ? b4 : b2;
        const void* rho = P ? rw2 : rw1;
        float* qp = s_q + P * 16;
        stage2s<3, DW>(0, Wa, Wan, fW, ba, s_union, s_inp, wave, lane);
        __syncthreads();
        stage3s<3, DW>(0, Wb, Wbn, fW, bb, rho, s_union, qp, wave, lane);
        __syncthreads();
        stage2s<2, DW>(3, Wa, Wan, fW, ba, s_union, s_inp, wave, lane);
        __syncthreads();
        stage3s<2, DW>(3, Wb, Wbn, fW, bb, rho, s_union, qp, wave, lane);
        __syncthreads();
    }

    if (tid < 16) {
        out[b0 + tid] = s_q[tid] + ldf(rb1, 0, fW);
        out[Btot + b0 + tid] = s_q[16 + tid] + ldf(rb2, 0, fW);
    }
}

extern "C" void kernel_launch(void* const* d_in, const int* in_sizes, int n_in,
                              void* d_out, int out_size, void* d_ws, size_t ws_size,
                              hipStream_t stream) {
    int B = out_size / 2;  // 16384

    const void *obs = nullptr, *act = nullptr, *ag = nullptr, *g = nullptr;
    const void *mp_w = nullptr, *mp_b = nullptr;
    const void *w1 = nullptr, *b1 = nullptr, *w2 = nullptr, *b2 = nullptr;
    const void *w3 = nullptr, *b3 = nullptr, *w4 = nullptr, *b4 = nullptr;
    const void *rw1 = nullptr, *rb1 = nullptr, *rw2 = nullptr, *rb2 = nullptr;
    const int *eA = nullptr, *eB = nullptr, *pred = nullptr, *inc = nullptr;
    int c30 = 0, c256 = 0, c1 = 0, c40k = 0, c65k = 0, c20 = 0;
    for (int i = 0; i < n_in; ++i) {
        int sz = in_sizes[i];
        const void* p = d_in[i];
        if (sz == B * 85) obs = p;
        else if (sz == B * 30) { if (c30++ == 0) ag = p; else g = p; }
        else if (sz == 5888) mp_w = p;
        else if (sz == 128) mp_b = p;
        else if (sz == 40192) { if (c40k++ == 0) w1 = p; else w3 = p; }
        else if (sz == 65536 || sz == B * 4) {
            int c = c65k++;
            if (c == 0) act = p; else if (c == 1) w2 = p; else w4 = p;
        }
        else if (sz == 256) {
            int c = c256++;
            if (c == 0) b1 = p; else if (c == 1) b2 = p; else if (c == 2) b3 = p;
            else if (c == 3) b4 = p; else if (c == 4) rw1 = p; else rw2 = p;
        }
        else if (sz == 1) { if (c1++ == 0) rb1 = p; else rb2 = p; }
        else if (sz == 40) pred = (const int*)p;
        else if (sz == 20) {
            int c = c20++;
            if (c == 0) eA = (const int*)p;
            else if (c == 1) eB = (const int*)p;
            else inc = (const int*)p;
        }
    }
    if (!obs || !act || !ag || !g || !mp_w || !mp_b || !w1 || !b1 || !w2 || !b2 ||
        !w3 || !b3 || !w4 || !b4 || !rw1 || !rb1 || !rw2 || !rb2 || !eA || !eB ||
        !pred || !inc) {
        obs = d_in[0]; act = d_in[1]; ag = d_in[2]; g = d_in[3];
        mp_w = d_in[4]; mp_b = d_in[5]; w1 = d_in[6]; b1 = d_in[7];
        w2 = d_in[8]; b2 = d_in[9]; w3 = d_in[10]; b3 = d_in[11];
        w4 = d_in[12]; b4 = d_in[13]; rw1 = d_in[14]; rb1 = d_in[15];
        rw2 = d_in[16]; rb2 = d_in[17];
        eA = (const int*)d_in[18]; eB = (const int*)d_in[19];
        pred = (const int*)d_in[20]; inc = (const int*)d_in[21];
    }

    float* out = (float*)d_out;
    __bf16* wsW = (__bf16*)d_ws;
    bool use_ws = ws_size >= WS_BYTES + 8;
    int* flags = (int*)((char*)d_ws + WS_BYTES);
    int grid = B / 16;

    if (use_ws) {
        swz<<<(WS_TOTAL + 255) / 256, 256, 0, stream>>>(
            mp_w, w1, w2, w3, w4, wsW, (const unsigned short*)obs, flags);
        gn_main<false><<<grid, 512, 0, stream>>>(
            obs, act, ag, g, mp_b, b1, b2, b3, b4, rw1, rb1, rw2, rb2,
            eA, eB, pred, inc, wsW, mp_w, w1, w2, w3, w4, flags, out, B);
    } else {
        gn_main<true><<<grid, 512, 0, stream>>>(
            obs, act, ag, g, mp_b, b1, b2, b3, b4, rw1, rb1, rw2, rb2,
            eA, eB, pred, inc, wsW, mp_w, w1, w2, w3, w4, flags, out, B);
    }
}

// Round 9
// 172.527 us; speedup vs baseline: 2.2578x; 1.0349x over previous
//
#include <hip/hip_runtime.h>
#include <hip/hip_bf16.h>

typedef __bf16 bf16x8 __attribute__((ext_vector_type(8)));
typedef __bf16 bf16x4 __attribute__((ext_vector_type(4)));
typedef float f32x4 __attribute__((ext_vector_type(4)));

#define MFMA(a, b, c) __builtin_amdgcn_mfma_f32_16x16x32_bf16(a, b, c, 0, 0, 0)

// ws layout (bf16 elem offsets) — weights in MFMA B-fragment order:
// frag[(nt*nKT + kt)*64 + lane][j] = W[kt*32 + (lane>>4)*8 + j][nt*16 + (lane&15)]
constexpr int MP_OFF = 0;
constexpr int W1_OFF = 8192;
constexpr int W2_OFF = 49152;
constexpr int W3_OFF = 114688;
constexpr int W4_OFF = 155648;
constexpr int WS_TOTAL = 221184;
constexpr size_t WS_BYTES = (size_t)WS_TOTAL * 2;

__device__ __forceinline__ float ldf(const void* p, int i, bool f32) {
    return f32 ? ((const float*)p)[i] : (float)(((const __bf16*)p)[i]);
}
__device__ __forceinline__ int geti(const int* p, int i, bool i64) {
    return p[i64 ? 2 * i : i];
}

// Read-side swizzle with fused dtype self-detect (fp32 misread as bf16 shows
// exponent-0xFF halfwords, i.e. (h & 0x7F80) == 0x7F80). Block 0 publishes
// flags for gn_main. R9: vectorized detect (uint4, 4 iters vs 32 scalar) and
// 4 elems/thread (grid 864 -> 216; 4x less redundant detect traffic). The 4
// consecutive idx share segment/kp/row: boundaries are 4096-aligned and
// local is 4-aligned, so one bf16x4/float4 source load covers all 4.
__global__ void swz(const void* __restrict__ mp, const void* __restrict__ w1,
                    const void* __restrict__ w2, const void* __restrict__ w3,
                    const void* __restrict__ w4, __bf16* __restrict__ ws,
                    const unsigned short* __restrict__ uo, int* __restrict__ flags) {
    __shared__ int s_fw, s_fi;
    int tid = threadIdx.x;
    if (tid == 0) { s_fw = 0; s_fi = 0; }
    __syncthreads();
    const uint4* uw4 = (const uint4*)w2;
    int d = 0;
    for (int j = tid; j < 1024; j += 256) {
        uint4 v = uw4[j];
        unsigned x0 = v.x, x1 = v.y, x2 = v.z, x3 = v.w;
        if ((x0 & 0x7F80u) == 0x7F80u || ((x0 >> 16) & 0x7F80u) == 0x7F80u) d = 1;
        if ((x1 & 0x7F80u) == 0x7F80u || ((x1 >> 16) & 0x7F80u) == 0x7F80u) d = 1;
        if ((x2 & 0x7F80u) == 0x7F80u || ((x2 >> 16) & 0x7F80u) == 0x7F80u) d = 1;
        if ((x3 & 0x7F80u) == 0x7F80u || ((x3 >> 16) & 0x7F80u) == 0x7F80u) d = 1;
    }
    if (d) atomicOr(&s_fw, 1);
    if (blockIdx.x == 0) {
        const uint4* uo4 = (const uint4*)uo;
        int d0 = 0;
        for (int j = tid; j < 1024; j += 256) {
            uint4 v = uo4[j];
            unsigned x0 = v.x, x1 = v.y, x2 = v.z, x3 = v.w;
            if ((x0 & 0x7F80u) == 0x7F80u || ((x0 >> 16) & 0x7F80u) == 0x7F80u) d0 = 1;
            if ((x1 & 0x7F80u) == 0x7F80u || ((x1 >> 16) & 0x7F80u) == 0x7F80u) d0 = 1;
            if ((x2 & 0x7F80u) == 0x7F80u || ((x2 >> 16) & 0x7F80u) == 0x7F80u) d0 = 1;
            if ((x3 & 0x7F80u) == 0x7F80u || ((x3 >> 16) & 0x7F80u) == 0x7F80u) d0 = 1;
        }
        if (d0) atomicOr(&s_fi, 1);
    }
    __syncthreads();
    bool f32 = s_fw != 0;
    if (blockIdx.x == 0 && tid == 0) { flags[0] = s_fi; flags[1] = s_fw; }

    int idx0 = (blockIdx.x * 256 + tid) * 4;
    if (idx0 >= WS_TOTAL) return;
    const void* src;
    int base, nKT, nsh, style, K;
    if (idx0 < W1_OFF)      { src = mp; base = MP_OFF; nKT = 2; nsh = 7; style = 0; K = 46; }
    else if (idx0 < W2_OFF) { src = w1; base = W1_OFF; nKT = 5; nsh = 8; style = 1; K = 157; }
    else if (idx0 < W3_OFF) { src = w2; base = W2_OFF; nKT = 8; nsh = 8; style = 0; K = 256; }
    else if (idx0 < W4_OFF) { src = w3; base = W3_OFF; nKT = 5; nsh = 8; style = 1; K = 157; }
    else                    { src = w4; base = W4_OFF; nKT = 8; nsh = 8; style = 0; K = 256; }
    int N = 1 << nsh;
    int local0 = idx0 - base;
    int kp = local0 >> nsh, n0 = local0 & (N - 1);
    int ks = kp;
    bool ok = true;
    if (style == 1) { if (kp >= 32) ks = kp - 3; else if (kp >= 29) ok = false; }
    if (ks >= K) ok = false;
    float v0 = 0.f, v1 = 0.f, v2 = 0.f, v3 = 0.f;
    if (ok) {
        int so = (ks * N + n0) >> 2;  // elem offset /4; 4-aligned by construction
        if (f32) {
            float4 t = ((const float4*)src)[so];
            v0 = t.x; v1 = t.y; v2 = t.z; v3 = t.w;
        } else {
            bf16x4 t = ((const bf16x4*)src)[so];
            v0 = (float)t[0]; v1 = (float)t[1]; v2 = (float)t[2]; v3 = (float)t[3];
        }
    }
    int dst0 = ((n0 >> 4) * nKT + (kp >> 5)) * 512 +
               (((((kp >> 3) & 3)) << 4) | (n0 & 15)) * 8 + (kp & 7);
    ws[base + dst0] = (__bf16)v0;
    ws[base + dst0 + 8] = (__bf16)v1;
    ws[base + dst0 + 16] = (__bf16)v2;
    ws[base + dst0 + 24] = (__bf16)v3;
}

// Direct B-fragment gather fallback (ws too small). Same lane mapping as A-frag.
__device__ __forceinline__ bf16x8 gatherB(const void* W, bool f32, int style,
                                          int K, int N, int k0, int n, int q) {
    bf16x8 r;
#pragma unroll
    for (int j = 0; j < 8; ++j) {
        int k = k0 + q * 8 + j;
        bool ok = true;
        if (style == 1) { if (k >= 32) k -= 3; else if (k >= 29) ok = false; }
        if (k >= K) ok = false;
        float v = ok ? ldf(W, k * N + n, f32) : 0.f;
        r[j] = (__bf16)v;
    }
    return r;
}

// ROUND-1 STRUCTURE — the measured optimum of this session (gn_main untouched).
// Verified clean counters: FETCH~6.7MB, WRITE~0.13MB, VGPR 40, ~85us.
// Negative results (do NOT reintroduce without new evidence):
//   * s_setprio around MFMA clusters: −10% (R7; starves co-resident blocks'
//     staging phases — all 8 waves are barrier-lockstep here, no role split).
//   * Any 4-blocks/CU restructure (R3/R4/R5): 100-650MB anomalous scratch
//     traffic regardless of launch bounds; needs ScratchSize/disasm to chase.
//   * Global-scratch s_inp (R2): spills through L2 to HBM, 2.3TB/s-bound.
// LDS (50,544 B; 512-thr blocks, 8 waves; 3 blocks/CU):
//   s_union[0..8192)   : edge-A frags (PC<=8) — later h frags span [0..12288)
//   s_union[8192..10112): rowbuf 16 x 120 (dead before first h write)
//   s_inp[12800]       : inp frags, 5 mt x 5 kt x 512
template <int PC, int PBASE>
__device__ __forceinline__ void buildA(__bf16* sA, const __bf16* rb, const int* s_esrc,
                                       const int* s_pid0, const int* s_pid1, int tid) {
    for (int i = tid; i < 16 * PC * 8; i += 512) {
        int t = i >> 6, lanep = i & 63;
        int oct = ((t & 1) << 2) | (lanep >> 4);
        int r = (t >> 1) * 16 + (lanep & 15);
        int lb = r / PC, p = PBASE + r % PC;
        const __bf16* row = rb + lb * 120;
        bf16x8 v;
#pragma unroll
        for (int j = 0; j < 8; ++j) {
            int k = oct * 8 + j;
            __bf16 x = (__bf16)0.f;
            if (k < 10) x = row[k];
            else if (k < 14) x = row[85 + (k - 10)];
            else if (k < 16) x = row[89 + ((k == 14) ? s_pid0[p] : s_pid1[p])];
            else if (k < 31) x = row[10 + s_esrc[p] * 15 + (k - 16)];
            else if (k < 46) x = row[10 + (p >> 2) * 15 + (k - 31)];
            v[j] = x;
        }
        *(bf16x8*)(sA + t * 512 + lanep * 8) = v;
    }
}

// stage1: A=edges, B=mp_w frags; 8 waves x 1 nt; bw hoisted, flat m loop.
template <int PC, int PBASE, bool DW>
__device__ __forceinline__ void stage1(const __bf16* Wf, const void* Wn, bool fW,
                                       const void* mp_b, const __bf16* sA,
                                       __bf16* s_inp, int wave, int lane) {
    int q = lane >> 4, c = lane & 15;
    int nt = wave;
    float mb = ldf(mp_b, nt * 16 + c, fW);
    bf16x8 bw[2];
#pragma unroll
    for (int kt = 0; kt < 2; ++kt) {
        if constexpr (DW) bw[kt] = gatherB(Wn, fW, 0, 46, 128, kt * 32, nt * 16 + c, q);
        else bw[kt] = *(const bf16x8*)(Wf + (nt * 2 + kt) * 512 + lane * 8);
    }
    f32x4 zero4 = {0.f, 0.f, 0.f, 0.f};
#pragma unroll
    for (int m = 0; m < PC; ++m) {
        f32x4 acc = zero4;
#pragma unroll
        for (int kt = 0; kt < 2; ++kt) {
            bf16x8 a = *(const bf16x8*)(sA + (m * 2 + kt) * 512 + lane * 8);
            acc = MFMA(a, bw[kt], acc);
        }
        float sum = 0.f;
#pragma unroll
        for (int rr = 0; rr < 4; ++rr) {
            float z = acc[rr] + mb;
            sum += (z > 0.f) ? z : 0.f;
        }
        int r0 = m * 16 + q * 4;          // PC in {8,4}: pow2 div/mod, groups of 4 intact
        int lb = r0 / PC;
        int o = (PBASE + r0 % PC) >> 2;
        int rinp = lb * 5 + o;
        int kk = 32 + nt * 16 + c;
        s_inp[((rinp >> 4) * 5 + (kk >> 5)) * 512 +
              ((((kk & 31) >> 3) << 4) + (rinp & 15)) * 8 + (kk & 7)] = (__bf16)sum;
    }
}

// stage2 SWAPPED: D'[hcol][row] = MFMA(A=W1-frag, B=inp-frag); kt outer so each
// inp b-frag is read ONCE (shared across both n).
template <int MTN, bool DW>
__device__ __forceinline__ void stage2s(int mbase, const __bf16* Wf, const void* Wn,
                                        bool fW, const void* Ba, __bf16* s_h,
                                        const __bf16* s_inp, int wave, int lane) {
    int q = lane >> 4, c = lane & 15;
    f32x4 zero4 = {0.f, 0.f, 0.f, 0.f};
    f32x4 acc[2][MTN];
#pragma unroll
    for (int n = 0; n < 2; ++n)
#pragma unroll
        for (int m = 0; m < MTN; ++m) acc[n][m] = zero4;
#pragma unroll
    for (int kt = 0; kt < 5; ++kt) {
        bf16x8 b[MTN];
#pragma unroll
        for (int m = 0; m < MTN; ++m)
            b[m] = *(const bf16x8*)(s_inp + ((mbase + m) * 5 + kt) * 512 + lane * 8);
#pragma unroll
        for (int n = 0; n < 2; ++n) {
            int ht = wave * 2 + n;
            bf16x8 aw;
            if constexpr (DW) aw = gatherB(Wn, fW, 1, 157, 256, kt * 32, ht * 16 + c, q);
            else aw = *(const bf16x8*)(Wf + (ht * 5 + kt) * 512 + lane * 8);
#pragma unroll
            for (int m = 0; m < MTN; ++m) acc[n][m] = MFMA(aw, b[m], acc[n][m]);
        }
    }
    float bias_r[2][4];
#pragma unroll
    for (int n = 0; n < 2; ++n)
#pragma unroll
        for (int rg = 0; rg < 4; ++rg)
            bias_r[n][rg] = ldf(Ba, (wave * 2 + n) * 16 + q * 4 + rg, fW);
#pragma unroll
    for (int n = 0; n < 2; ++n) {
        int ht = wave * 2 + n;
#pragma unroll
        for (int m = 0; m < MTN; ++m) {
            bf16x4 hv;
#pragma unroll
            for (int rg = 0; rg < 4; ++rg) {
                float z = acc[n][m][rg] + bias_r[n][rg];
                hv[rg] = (__bf16)((z > 0.f) ? z : 0.f);
            }
            *(bf16x4*)(s_h + (m * 8 + (ht >> 1)) * 512 +
                       ((((ht & 1) * 2 + (q >> 1)) << 4) | c) * 8 + ((q & 1) << 2)) = hv;
        }
    }
}

// stage3 SWAPPED: D'[ncol][row] = MFMA(A=W2-frag, B=h-frag); kt outer, h b-frags
// read once per kt (shared across both n).
template <int MTN, bool DW>
__device__ __forceinline__ void stage3s(int mbase, const __bf16* Wf, const void* Wn,
                                        bool fW, const void* Bb, const void* Rh,
                                        const __bf16* s_h, float* s_qp, int wave, int lane) {
    int q = lane >> 4, c = lane & 15;
    f32x4 zero4 = {0.f, 0.f, 0.f, 0.f};
    f32x4 acc[2][MTN];
#pragma unroll
    for (int n = 0; n < 2; ++n)
#pragma unroll
        for (int m = 0; m < MTN; ++m) acc[n][m] = zero4;
#pragma unroll
    for (int kt = 0; kt < 8; ++kt) {
        bf16x8 b[MTN];
#pragma unroll
        for (int m = 0; m < MTN; ++m)
            b[m] = *(const bf16x8*)(s_h + (m * 8 + kt) * 512 + lane * 8);
#pragma unroll
        for (int n = 0; n < 2; ++n) {
            int nt = wave * 2 + n;
            bf16x8 aw;
            if constexpr (DW) aw = gatherB(Wn, fW, 0, 256, 256, kt * 32, nt * 16 + c, q);
            else aw = *(const bf16x8*)(Wf + (nt * 8 + kt) * 512 + lane * 8);
#pragma unroll
            for (int m = 0; m < MTN; ++m) acc[n][m] = MFMA(aw, b[m], acc[n][m]);
        }
    }
    float bias_r[2][4], rho_r[2][4];
#pragma unroll
    for (int n = 0; n < 2; ++n)
#pragma unroll
        for (int rg = 0; rg < 4; ++rg) {
            int ncol = (wave * 2 + n) * 16 + q * 4 + rg;
            bias_r[n][rg] = ldf(Bb, ncol, fW);
            rho_r[n][rg] = ldf(Rh, ncol, fW);
        }
    float rowsum[MTN];
#pragma unroll
    for (int m = 0; m < MTN; ++m) rowsum[m] = 0.f;
#pragma unroll
    for (int n = 0; n < 2; ++n)
#pragma unroll
        for (int m = 0; m < MTN; ++m)
#pragma unroll
            for (int rg = 0; rg < 4; ++rg) {
                float z = acc[n][m][rg] + bias_r[n][rg];
                z = (z > 0.f) ? z : 0.f;
                rowsum[m] += z * rho_r[n][rg];
            }
#pragma unroll
    for (int m = 0; m < MTN; ++m) {
        float v = rowsum[m];
        v += __shfl_xor(v, 16);
        v += __shfl_xor(v, 32);
        if (q == 0) {
            int r0 = (mbase + m) * 16 + c;  // rinp = b*5+o
            atomicAdd(&s_qp[r0 / 5], v);
        }
    }
}

template <bool DW>
__global__ __launch_bounds__(512, 6) void gn_main(
    const void* __restrict__ obs, const void* __restrict__ act,
    const void* __restrict__ ag, const void* __restrict__ g,
    const void* __restrict__ mp_b, const void* __restrict__ b1,
    const void* __restrict__ b2, const void* __restrict__ b3,
    const void* __restrict__ b4, const void* __restrict__ rw1,
    const void* __restrict__ rb1, const void* __restrict__ rw2,
    const void* __restrict__ rb2, const int* __restrict__ eA,
    const int* __restrict__ eB, const int* __restrict__ pred_ids,
    const int* __restrict__ incoming, const __bf16* __restrict__ wsW,
    const void* __restrict__ mp_w, const void* __restrict__ w1,
    const void* __restrict__ w2, const void* __restrict__ w3,
    const void* __restrict__ w4, const int* __restrict__ flags,
    float* __restrict__ out, int Btot) {
    __shared__ __align__(16) __bf16 s_union[12288];
    __shared__ __align__(16) __bf16 s_inp[12800];
    __shared__ __align__(16) float s_q[32];
    __shared__ int s_esrc[20], s_pid0[20], s_pid1[20];

    int tid = threadIdx.x, lane = tid & 63, wave = tid >> 6;
    __bf16* rb = s_union + 8192;  // [8192,10112): outside buildA region; dead before h
    int b0 = blockIdx.x * 16;

    // ---- dtype flags ----
    bool fI, fW;
    if constexpr (DW) {
        const unsigned short* uo = (const unsigned short*)obs;
        const unsigned short* uw = (const unsigned short*)w2;
        int d0 = 0, d1 = 0;
        for (int i = lane; i < 8192; i += 64) {
            if (((uo[i] >> 7) & 0xFF) == 0xFF) d0 = 1;
            if (((uw[i] >> 7) & 0xFF) == 0xFF) d1 = 1;
        }
        fI = __ballot(d0) != 0;
        fW = __ballot(d1) != 0;
    } else {
        fI = flags[0] != 0;
        fW = flags[1] != 0;
    }

    // ---- int width + src/dst disambiguation ----
    bool i64_i = (incoming[1] == 0);
    bool i64_p = (pred_ids[1] == 0);
    bool i64_e = (eA[9] == 0);
    const int* es = (geti(eA, 4, i64_e) == 1) ? eA : eB;

    if (tid < 20) {
        int e = geti(incoming, tid, i64_i);  // tid = o*4+j; edge p=tid has dst o=tid/4
        s_esrc[tid] = geti(es, e, i64_e);
        s_pid0[tid] = geti(pred_ids, 2 * e, i64_p);
        s_pid1[tid] = geti(pred_ids, 2 * e + 1, i64_p);
    }

    for (int i = tid; i < 16 * 120; i += 512) {
        int lb = i / 120, cidx = i % 120;
        int bg = b0 + lb;
        float v = 0.f;
        if (cidx < 85) v = ldf(obs, bg * 85 + cidx, fI);
        else if (cidx < 89) v = ldf(act, bg * 4 + (cidx - 85), fI);
        else if (cidx < 119) {
            int t = cidx - 89;
            v = ldf(g, bg * 30 + t, fI) - ldf(ag, bg * 30 + t, fI);
        }
        rb[i] = (__bf16)v;
    }
    __syncthreads();

    // inp kt=0 plane (k<32), conflict-free mapping (lanep = i&63)
    for (int i = tid; i < 320; i += 512) {
        int mt = i >> 6, lanep = i & 63;
        int oct = lanep >> 4;
        int r = mt * 16 + (lanep & 15);
        int lb = r / 5, o = r % 5;
        const __bf16* row = rb + lb * 120;
        bf16x8 v;
#pragma unroll
        for (int j = 0; j < 8; ++j) {
            int k = oct * 8 + j;
            __bf16 x = (__bf16)0.f;
            if (k < 4) x = row[85 + k];
            else if (k < 14) x = row[k - 4];
            else if (k < 29) x = row[10 + o * 15 + (k - 14)];
            v[j] = x;
        }
        *(bf16x8*)(s_inp + mt * 2560 + lanep * 8) = v;
    }
    buildA<8, 0>(s_union, rb, s_esrc, s_pid0, s_pid1, tid);
    __syncthreads();
    stage1<8, 0, DW>(wsW + MP_OFF, mp_w, fW, mp_b, s_union, s_inp, wave, lane);
    __syncthreads();
    buildA<8, 8>(s_union, rb, s_esrc, s_pid0, s_pid1, tid);
    __syncthreads();
    stage1<8, 8, DW>(wsW + MP_OFF, mp_w, fW, mp_b, s_union, s_inp, wave, lane);
    __syncthreads();
    buildA<4, 16>(s_union, rb, s_esrc, s_pid0, s_pid1, tid);
    __syncthreads();
    stage1<4, 16, DW>(wsW + MP_OFF, mp_w, fW, mp_b, s_union, s_inp, wave, lane);
    if (tid < 32) s_q[tid] = 0.f;
    __syncthreads();

    for (int P = 0; P < 2; ++P) {
        const __bf16* Wa = wsW + (P ? W3_OFF : W1_OFF);
        const __bf16* Wb = wsW + (P ? W4_OFF : W2_OFF);
        const void* Wan = P ? w3 : w1;
        const void* Wbn = P ? w4 : w2;
        const void* ba = P ? b3 : b1;
        const void* bb = P ? b4 : b2;
        const void* rho = P ? rw2 : rw1;
        float* qp = s_q + P * 16;
        stage2s<3, DW>(0, Wa, Wan, fW, ba, s_union, s_inp, wave, lane);
        __syncthreads();
        stage3s<3, DW>(0, Wb, Wbn, fW, bb, rho, s_union, qp, wave, lane);
        __syncthreads();
        stage2s<2, DW>(3, Wa, Wan, fW, ba, s_union, s_inp, wave, lane);
        __syncthreads();
        stage3s<2, DW>(3, Wb, Wbn, fW, bb, rho, s_union, qp, wave, lane);
        __syncthreads();
    }

    if (tid < 16) {
        out[b0 + tid] = s_q[tid] + ldf(rb1, 0, fW);
        out[Btot + b0 + tid] = s_q[16 + tid] + ldf(rb2, 0, fW);
    }
}

extern "C" void kernel_launch(void* const* d_in, const int* in_sizes, int n_in,
                              void* d_out, int out_size, void* d_ws, size_t ws_size,
                              hipStream_t stream) {
    int B = out_size / 2;  // 16384

    const void *obs = nullptr, *act = nullptr, *ag = nullptr, *g = nullptr;
    const void *mp_w = nullptr, *mp_b = nullptr;
    const void *w1 = nullptr, *b1 = nullptr, *w2 = nullptr, *b2 = nullptr;
    const void *w3 = nullptr, *b3 = nullptr, *w4 = nullptr, *b4 = nullptr;
    const void *rw1 = nullptr, *rb1 = nullptr, *rw2 = nullptr, *rb2 = nullptr;
    const int *eA = nullptr, *eB = nullptr, *pred = nullptr, *inc = nullptr;
    int c30 = 0, c256 = 0, c1 = 0, c40k = 0, c65k = 0, c20 = 0;
    for (int i = 0; i < n_in; ++i) {
        int sz = in_sizes[i];
        const void* p = d_in[i];
        if (sz == B * 85) obs = p;
        else if (sz == B * 30) { if (c30++ == 0) ag = p; else g = p; }
        else if (sz == 5888) mp_w = p;
        else if (sz == 128) mp_b = p;
        else if (sz == 40192) { if (c40k++ == 0) w1 = p; else w3 = p; }
        else if (sz == 65536 || sz == B * 4) {
            int c = c65k++;
            if (c == 0) act = p; else if (c == 1) w2 = p; else w4 = p;
        }
        else if (sz == 256) {
            int c = c256++;
            if (c == 0) b1 = p; else if (c == 1) b2 = p; else if (c == 2) b3 = p;
            else if (c == 3) b4 = p; else if (c == 4) rw1 = p; else rw2 = p;
        }
        else if (sz == 1) { if (c1++ == 0) rb1 = p; else rb2 = p; }
        else if (sz == 40) pred = (const int*)p;
        else if (sz == 20) {
            int c = c20++;
            if (c == 0) eA = (const int*)p;
            else if (c == 1) eB = (const int*)p;
            else inc = (const int*)p;
        }
    }
    if (!obs || !act || !ag || !g || !mp_w || !mp_b || !w1 || !b1 || !w2 || !b2 ||
        !w3 || !b3 || !w4 || !b4 || !rw1 || !rb1 || !rw2 || !rb2 || !eA || !eB ||
        !pred || !inc) {
        obs = d_in[0]; act = d_in[1]; ag = d_in[2]; g = d_in[3];
        mp_w = d_in[4]; mp_b = d_in[5]; w1 = d_in[6]; b1 = d_in[7];
        w2 = d_in[8]; b2 = d_in[9]; w3 = d_in[10]; b3 = d_in[11];
        w4 = d_in[12]; b4 = d_in[13]; rw1 = d_in[14]; rb1 = d_in[15];
        rw2 = d_in[16]; rb2 = d_in[17];
        eA = (const int*)d_in[18]; eB = (const int*)d_in[19];
        pred = (const int*)d_in[20]; inc = (const int*)d_in[21];
    }

    float* out = (float*)d_out;
    __bf16* wsW = (__bf16*)d_ws;
    bool use_ws = ws_size >= WS_BYTES + 8;
    int* flags = (int*)((char*)d_ws + WS_BYTES);
    int grid = B / 16;

    if (use_ws) {
        swz<<<WS_TOTAL / 1024, 256, 0, stream>>>(
            mp_w, w1, w2, w3, w4, wsW, (const unsigned short*)obs, flags);
        gn_main<false><<<grid, 512, 0, stream>>>(
            obs, act, ag, g, mp_b, b1, b2, b3, b4, rw1, rb1, rw2, rb2,
            eA, eB, pred, inc, wsW, mp_w, w1, w2, w3, w4, flags, out, B);
    } else {
        gn_main<true><<<grid, 512, 0, stream>>>(
            obs, act, ag, g, mp_b, b1, b2, b3, b4, rw1, rb1, rw2, rb2,
            eA, eB, pred, inc, wsW, mp_w, w1, w2, w3, w4, flags, out, B);
    }
}

// Round 10
// 170.611 us; speedup vs baseline: 2.2831x; 1.0112x over previous
//
#include <hip/hip_runtime.h>
#include <hip/hip_bf16.h>

typedef __bf16 bf16x8 __attribute__((ext_vector_type(8)));
typedef __bf16 bf16x4 __attribute__((ext_vector_type(4)));
typedef float f32x4 __attribute__((ext_vector_type(4)));

#define MFMA(a, b, c) __builtin_amdgcn_mfma_f32_16x16x32_bf16(a, b, c, 0, 0, 0)

// ws layout (bf16 elem offsets) — weights in MFMA B-fragment order:
// frag[(nt*nKT + kt)*64 + lane][j] = W[kt*32 + (lane>>4)*8 + j][nt*16 + (lane&15)]
constexpr int MP_OFF = 0;
constexpr int W1_OFF = 8192;
constexpr int W2_OFF = 49152;
constexpr int W3_OFF = 114688;
constexpr int W4_OFF = 155648;
constexpr int WS_TOTAL = 221184;
constexpr size_t WS_BYTES = (size_t)WS_TOTAL * 2;

__device__ __forceinline__ float ldf(const void* p, int i, bool f32) {
    return f32 ? ((const float*)p)[i] : (float)(((const __bf16*)p)[i]);
}
__device__ __forceinline__ int geti(const int* p, int i, bool i64) {
    return p[i64 ? 2 * i : i];
}

// Read-side swizzle with fused dtype self-detect (fp32 misread as bf16 shows
// exponent-0xFF halfwords, i.e. (h & 0x7F80) == 0x7F80). Block 0 publishes
// flags for gn_main. R10: 8 elems/thread (grid 216 -> 108; detect traffic
// halves again). Segment boundaries are 2048-divisible and local0 is
// 8-aligned, so the 8 consecutive idx share segment/kp/(n>>4): one bf16x8
// (or 2x float4) source load, dst = dst0 + 8j. Full 8192-halfword detect
// scan kept (sampling fewer would raise miss prob to ~2%).
__global__ void swz(const void* __restrict__ mp, const void* __restrict__ w1,
                    const void* __restrict__ w2, const void* __restrict__ w3,
                    const void* __restrict__ w4, __bf16* __restrict__ ws,
                    const unsigned short* __restrict__ uo, int* __restrict__ flags) {
    __shared__ int s_fw, s_fi;
    int tid = threadIdx.x;
    if (tid == 0) { s_fw = 0; s_fi = 0; }
    __syncthreads();
    const uint4* uw4 = (const uint4*)w2;
    int d = 0;
    for (int j = tid; j < 1024; j += 256) {
        uint4 v = uw4[j];
        unsigned x0 = v.x, x1 = v.y, x2 = v.z, x3 = v.w;
        if ((x0 & 0x7F80u) == 0x7F80u || ((x0 >> 16) & 0x7F80u) == 0x7F80u) d = 1;
        if ((x1 & 0x7F80u) == 0x7F80u || ((x1 >> 16) & 0x7F80u) == 0x7F80u) d = 1;
        if ((x2 & 0x7F80u) == 0x7F80u || ((x2 >> 16) & 0x7F80u) == 0x7F80u) d = 1;
        if ((x3 & 0x7F80u) == 0x7F80u || ((x3 >> 16) & 0x7F80u) == 0x7F80u) d = 1;
    }
    if (d) atomicOr(&s_fw, 1);
    if (blockIdx.x == 0) {
        const uint4* uo4 = (const uint4*)uo;
        int d0 = 0;
        for (int j = tid; j < 1024; j += 256) {
            uint4 v = uo4[j];
            unsigned x0 = v.x, x1 = v.y, x2 = v.z, x3 = v.w;
            if ((x0 & 0x7F80u) == 0x7F80u || ((x0 >> 16) & 0x7F80u) == 0x7F80u) d0 = 1;
            if ((x1 & 0x7F80u) == 0x7F80u || ((x1 >> 16) & 0x7F80u) == 0x7F80u) d0 = 1;
            if ((x2 & 0x7F80u) == 0x7F80u || ((x2 >> 16) & 0x7F80u) == 0x7F80u) d0 = 1;
            if ((x3 & 0x7F80u) == 0x7F80u || ((x3 >> 16) & 0x7F80u) == 0x7F80u) d0 = 1;
        }
        if (d0) atomicOr(&s_fi, 1);
    }
    __syncthreads();
    bool f32 = s_fw != 0;
    if (blockIdx.x == 0 && tid == 0) { flags[0] = s_fi; flags[1] = s_fw; }

    int idx0 = (blockIdx.x * 256 + tid) * 8;
    if (idx0 >= WS_TOTAL) return;
    const void* src;
    int base, nKT, nsh, style, K;
    if (idx0 < W1_OFF)      { src = mp; base = MP_OFF; nKT = 2; nsh = 7; style = 0; K = 46; }
    else if (idx0 < W2_OFF) { src = w1; base = W1_OFF; nKT = 5; nsh = 8; style = 1; K = 157; }
    else if (idx0 < W3_OFF) { src = w2; base = W2_OFF; nKT = 8; nsh = 8; style = 0; K = 256; }
    else if (idx0 < W4_OFF) { src = w3; base = W3_OFF; nKT = 5; nsh = 8; style = 1; K = 157; }
    else                    { src = w4; base = W4_OFF; nKT = 8; nsh = 8; style = 0; K = 256; }
    int N = 1 << nsh;
    int local0 = idx0 - base;
    int kp = local0 >> nsh, n0 = local0 & (N - 1);
    int ks = kp;
    bool ok = true;
    if (style == 1) { if (kp >= 32) ks = kp - 3; else if (kp >= 29) ok = false; }
    if (ks >= K) ok = false;
    float v[8];
#pragma unroll
    for (int j = 0; j < 8; ++j) v[j] = 0.f;
    if (ok) {
        int e0 = ks * N + n0;  // 8-aligned by construction
        if (f32) {
            float4 ta = ((const float4*)src)[e0 >> 2];
            float4 tb = ((const float4*)src)[(e0 >> 2) + 1];
            v[0] = ta.x; v[1] = ta.y; v[2] = ta.z; v[3] = ta.w;
            v[4] = tb.x; v[5] = tb.y; v[6] = tb.z; v[7] = tb.w;
        } else {
            bf16x8 t = ((const bf16x8*)src)[e0 >> 3];
#pragma unroll
            for (int j = 0; j < 8; ++j) v[j] = (float)t[j];
        }
    }
    int dst0 = ((n0 >> 4) * nKT + (kp >> 5)) * 512 +
               (((((kp >> 3) & 3)) << 4) | (n0 & 15)) * 8 + (kp & 7);
#pragma unroll
    for (int j = 0; j < 8; ++j)
        ws[base + dst0 + 8 * j] = (__bf16)v[j];
}

// Direct B-fragment gather fallback (ws too small). Same lane mapping as A-frag.
__device__ __forceinline__ bf16x8 gatherB(const void* W, bool f32, int style,
                                          int K, int N, int k0, int n, int q) {
    bf16x8 r;
#pragma unroll
    for (int j = 0; j < 8; ++j) {
        int k = k0 + q * 8 + j;
        bool ok = true;
        if (style == 1) { if (k >= 32) k -= 3; else if (k >= 29) ok = false; }
        if (k >= K) ok = false;
        float v = ok ? ldf(W, k * N + n, f32) : 0.f;
        r[j] = (__bf16)v;
    }
    return r;
}

// ROUND-1 STRUCTURE — the measured optimum of this session (gn_main untouched).
// Verified clean counters: FETCH~6.7MB, WRITE~0.13MB, VGPR 40, ~81us.
// Negative results (do NOT reintroduce without new evidence):
//   * s_setprio around MFMA clusters: −10% (R7; starves co-resident blocks'
//     staging phases — all 8 waves are barrier-lockstep here, no role split).
//   * Any 4-blocks/CU restructure (R3/R4/R5): 100-650MB anomalous scratch
//     traffic regardless of launch bounds; needs ScratchSize/disasm to chase.
//   * Global-scratch s_inp (R2): spills through L2 to HBM, 2.3TB/s-bound.
// LDS (50,544 B; 512-thr blocks, 8 waves; 3 blocks/CU):
//   s_union[0..8192)   : edge-A frags (PC<=8) — later h frags span [0..12288)
//   s_union[8192..10112): rowbuf 16 x 120 (dead before first h write)
//   s_inp[12800]       : inp frags, 5 mt x 5 kt x 512
template <int PC, int PBASE>
__device__ __forceinline__ void buildA(__bf16* sA, const __bf16* rb, const int* s_esrc,
                                       const int* s_pid0, const int* s_pid1, int tid) {
    for (int i = tid; i < 16 * PC * 8; i += 512) {
        int t = i >> 6, lanep = i & 63;
        int oct = ((t & 1) << 2) | (lanep >> 4);
        int r = (t >> 1) * 16 + (lanep & 15);
        int lb = r / PC, p = PBASE + r % PC;
        const __bf16* row = rb + lb * 120;
        bf16x8 v;
#pragma unroll
        for (int j = 0; j < 8; ++j) {
            int k = oct * 8 + j;
            __bf16 x = (__bf16)0.f;
            if (k < 10) x = row[k];
            else if (k < 14) x = row[85 + (k - 10)];
            else if (k < 16) x = row[89 + ((k == 14) ? s_pid0[p] : s_pid1[p])];
            else if (k < 31) x = row[10 + s_esrc[p] * 15 + (k - 16)];
            else if (k < 46) x = row[10 + (p >> 2) * 15 + (k - 31)];
            v[j] = x;
        }
        *(bf16x8*)(sA + t * 512 + lanep * 8) = v;
    }
}

// stage1: A=edges, B=mp_w frags; 8 waves x 1 nt; bw hoisted, flat m loop.
template <int PC, int PBASE, bool DW>
__device__ __forceinline__ void stage1(const __bf16* Wf, const void* Wn, bool fW,
                                       const void* mp_b, const __bf16* sA,
                                       __bf16* s_inp, int wave, int lane) {
    int q = lane >> 4, c = lane & 15;
    int nt = wave;
    float mb = ldf(mp_b, nt * 16 + c, fW);
    bf16x8 bw[2];
#pragma unroll
    for (int kt = 0; kt < 2; ++kt) {
        if constexpr (DW) bw[kt] = gatherB(Wn, fW, 0, 46, 128, kt * 32, nt * 16 + c, q);
        else bw[kt] = *(const bf16x8*)(Wf + (nt * 2 + kt) * 512 + lane * 8);
    }
    f32x4 zero4 = {0.f, 0.f, 0.f, 0.f};
#pragma unroll
    for (int m = 0; m < PC; ++m) {
        f32x4 acc = zero4;
#pragma unroll
        for (int kt = 0; kt < 2; ++kt) {
            bf16x8 a = *(const bf16x8*)(sA + (m * 2 + kt) * 512 + lane * 8);
            acc = MFMA(a, bw[kt], acc);
        }
        float sum = 0.f;
#pragma unroll
        for (int rr = 0; rr < 4; ++rr) {
            float z = acc[rr] + mb;
            sum += (z > 0.f) ? z : 0.f;
        }
        int r0 = m * 16 + q * 4;          // PC in {8,4}: pow2 div/mod, groups of 4 intact
        int lb = r0 / PC;
        int o = (PBASE + r0 % PC) >> 2;
        int rinp = lb * 5 + o;
        int kk = 32 + nt * 16 + c;
        s_inp[((rinp >> 4) * 5 + (kk >> 5)) * 512 +
              ((((kk & 31) >> 3) << 4) + (rinp & 15)) * 8 + (kk & 7)] = (__bf16)sum;
    }
}

// stage2 SWAPPED: D'[hcol][row] = MFMA(A=W1-frag, B=inp-frag); kt outer so each
// inp b-frag is read ONCE (shared across both n).
template <int MTN, bool DW>
__device__ __forceinline__ void stage2s(int mbase, const __bf16* Wf, const void* Wn,
                                        bool fW, const void* Ba, __bf16* s_h,
                                        const __bf16* s_inp, int wave, int lane) {
    int q = lane >> 4, c = lane & 15;
    f32x4 zero4 = {0.f, 0.f, 0.f, 0.f};
    f32x4 acc[2][MTN];
#pragma unroll
    for (int n = 0; n < 2; ++n)
#pragma unroll
        for (int m = 0; m < MTN; ++m) acc[n][m] = zero4;
#pragma unroll
    for (int kt = 0; kt < 5; ++kt) {
        bf16x8 b[MTN];
#pragma unroll
        for (int m = 0; m < MTN; ++m)
            b[m] = *(const bf16x8*)(s_inp + ((mbase + m) * 5 + kt) * 512 + lane * 8);
#pragma unroll
        for (int n = 0; n < 2; ++n) {
            int ht = wave * 2 + n;
            bf16x8 aw;
            if constexpr (DW) aw = gatherB(Wn, fW, 1, 157, 256, kt * 32, ht * 16 + c, q);
            else aw = *(const bf16x8*)(Wf + (ht * 5 + kt) * 512 + lane * 8);
#pragma unroll
            for (int m = 0; m < MTN; ++m) acc[n][m] = MFMA(aw, b[m], acc[n][m]);
        }
    }
    float bias_r[2][4];
#pragma unroll
    for (int n = 0; n < 2; ++n)
#pragma unroll
        for (int rg = 0; rg < 4; ++rg)
            bias_r[n][rg] = ldf(Ba, (wave * 2 + n) * 16 + q * 4 + rg, fW);
#pragma unroll
    for (int n = 0; n < 2; ++n) {
        int ht = wave * 2 + n;
#pragma unroll
        for (int m = 0; m < MTN; ++m) {
            bf16x4 hv;
#pragma unroll
            for (int rg = 0; rg < 4; ++rg) {
                float z = acc[n][m][rg] + bias_r[n][rg];
                hv[rg] = (__bf16)((z > 0.f) ? z : 0.f);
            }
            *(bf16x4*)(s_h + (m * 8 + (ht >> 1)) * 512 +
                       ((((ht & 1) * 2 + (q >> 1)) << 4) | c) * 8 + ((q & 1) << 2)) = hv;
        }
    }
}

// stage3 SWAPPED: D'[ncol][row] = MFMA(A=W2-frag, B=h-frag); kt outer, h b-frags
// read once per kt (shared across both n).
template <int MTN, bool DW>
__device__ __forceinline__ void stage3s(int mbase, const __bf16* Wf, const void* Wn,
                                        bool fW, const void* Bb, const void* Rh,
                                        const __bf16* s_h, float* s_qp, int wave, int lane) {
    int q = lane >> 4, c = lane & 15;
    f32x4 zero4 = {0.f, 0.f, 0.f, 0.f};
    f32x4 acc[2][MTN];
#pragma unroll
    for (int n = 0; n < 2; ++n)
#pragma unroll
        for (int m = 0; m < MTN; ++m) acc[n][m] = zero4;
#pragma unroll
    for (int kt = 0; kt < 8; ++kt) {
        bf16x8 b[MTN];
#pragma unroll
        for (int m = 0; m < MTN; ++m)
            b[m] = *(const bf16x8*)(s_h + (m * 8 + kt) * 512 + lane * 8);
#pragma unroll
        for (int n = 0; n < 2; ++n) {
            int nt = wave * 2 + n;
            bf16x8 aw;
            if constexpr (DW) aw = gatherB(Wn, fW, 0, 256, 256, kt * 32, nt * 16 + c, q);
            else aw = *(const bf16x8*)(Wf + (nt * 8 + kt) * 512 + lane * 8);
#pragma unroll
            for (int m = 0; m < MTN; ++m) acc[n][m] = MFMA(aw, b[m], acc[n][m]);
        }
    }
    float bias_r[2][4], rho_r[2][4];
#pragma unroll
    for (int n = 0; n < 2; ++n)
#pragma unroll
        for (int rg = 0; rg < 4; ++rg) {
            int ncol = (wave * 2 + n) * 16 + q * 4 + rg;
            bias_r[n][rg] = ldf(Bb, ncol, fW);
            rho_r[n][rg] = ldf(Rh, ncol, fW);
        }
    float rowsum[MTN];
#pragma unroll
    for (int m = 0; m < MTN; ++m) rowsum[m] = 0.f;
#pragma unroll
    for (int n = 0; n < 2; ++n)
#pragma unroll
        for (int m = 0; m < MTN; ++m)
#pragma unroll
            for (int rg = 0; rg < 4; ++rg) {
                float z = acc[n][m][rg] + bias_r[n][rg];
                z = (z > 0.f) ? z : 0.f;
                rowsum[m] += z * rho_r[n][rg];
            }
#pragma unroll
    for (int m = 0; m < MTN; ++m) {
        float v = rowsum[m];
        v += __shfl_xor(v, 16);
        v += __shfl_xor(v, 32);
        if (q == 0) {
            int r0 = (mbase + m) * 16 + c;  // rinp = b*5+o
            atomicAdd(&s_qp[r0 / 5], v);
        }
    }
}

template <bool DW>
__global__ __launch_bounds__(512, 6) void gn_main(
    const void* __restrict__ obs, const void* __restrict__ act,
    const void* __restrict__ ag, const void* __restrict__ g,
    const void* __restrict__ mp_b, const void* __restrict__ b1,
    const void* __restrict__ b2, const void* __restrict__ b3,
    const void* __restrict__ b4, const void* __restrict__ rw1,
    const void* __restrict__ rb1, const void* __restrict__ rw2,
    const void* __restrict__ rb2, const int* __restrict__ eA,
    const int* __restrict__ eB, const int* __restrict__ pred_ids,
    const int* __restrict__ incoming, const __bf16* __restrict__ wsW,
    const void* __restrict__ mp_w, const void* __restrict__ w1,
    const void* __restrict__ w2, const void* __restrict__ w3,
    const void* __restrict__ w4, const int* __restrict__ flags,
    float* __restrict__ out, int Btot) {
    __shared__ __align__(16) __bf16 s_union[12288];
    __shared__ __align__(16) __bf16 s_inp[12800];
    __shared__ __align__(16) float s_q[32];
    __shared__ int s_esrc[20], s_pid0[20], s_pid1[20];

    int tid = threadIdx.x, lane = tid & 63, wave = tid >> 6;
    __bf16* rb = s_union + 8192;  // [8192,10112): outside buildA region; dead before h
    int b0 = blockIdx.x * 16;

    // ---- dtype flags ----
    bool fI, fW;
    if constexpr (DW) {
        const unsigned short* uo = (const unsigned short*)obs;
        const unsigned short* uw = (const unsigned short*)w2;
        int d0 = 0, d1 = 0;
        for (int i = lane; i < 8192; i += 64) {
            if (((uo[i] >> 7) & 0xFF) == 0xFF) d0 = 1;
            if (((uw[i] >> 7) & 0xFF) == 0xFF) d1 = 1;
        }
        fI = __ballot(d0) != 0;
        fW = __ballot(d1) != 0;
    } else {
        fI = flags[0] != 0;
        fW = flags[1] != 0;
    }

    // ---- int width + src/dst disambiguation ----
    bool i64_i = (incoming[1] == 0);
    bool i64_p = (pred_ids[1] == 0);
    bool i64_e = (eA[9] == 0);
    const int* es = (geti(eA, 4, i64_e) == 1) ? eA : eB;

    if (tid < 20) {
        int e = geti(incoming, tid, i64_i);  // tid = o*4+j; edge p=tid has dst o=tid/4
        s_esrc[tid] = geti(es, e, i64_e);
        s_pid0[tid] = geti(pred_ids, 2 * e, i64_p);
        s_pid1[tid] = geti(pred_ids, 2 * e + 1, i64_p);
    }

    for (int i = tid; i < 16 * 120; i += 512) {
        int lb = i / 120, cidx = i % 120;
        int bg = b0 + lb;
        float v = 0.f;
        if (cidx < 85) v = ldf(obs, bg * 85 + cidx, fI);
        else if (cidx < 89) v = ldf(act, bg * 4 + (cidx - 85), fI);
        else if (cidx < 119) {
            int t = cidx - 89;
            v = ldf(g, bg * 30 + t, fI) - ldf(ag, bg * 30 + t, fI);
        }
        rb[i] = (__bf16)v;
    }
    __syncthreads();

    // inp kt=0 plane (k<32), conflict-free mapping (lanep = i&63)
    for (int i = tid; i < 320; i += 512) {
        int mt = i >> 6, lanep = i & 63;
        int oct = lanep >> 4;
        int r = mt * 16 + (lanep & 15);
        int lb = r / 5, o = r % 5;
        const __bf16* row = rb + lb * 120;
        bf16x8 v;
#pragma unroll
        for (int j = 0; j < 8; ++j) {
            int k = oct * 8 + j;
            __bf16 x = (__bf16)0.f;
            if (k < 4) x = row[85 + k];
            else if (k < 14) x = row[k - 4];
            else if (k < 29) x = row[10 + o * 15 + (k - 14)];
            v[j] = x;
        }
        *(bf16x8*)(s_inp + mt * 2560 + lanep * 8) = v;
    }
    buildA<8, 0>(s_union, rb, s_esrc, s_pid0, s_pid1, tid);
    __syncthreads();
    stage1<8, 0, DW>(wsW + MP_OFF, mp_w, fW, mp_b, s_union, s_inp, wave, lane);
    __syncthreads();
    buildA<8, 8>(s_union, rb, s_esrc, s_pid0, s_pid1, tid);
    __syncthreads();
    stage1<8, 8, DW>(wsW + MP_OFF, mp_w, fW, mp_b, s_union, s_inp, wave, lane);
    __syncthreads();
    buildA<4, 16>(s_union, rb, s_esrc, s_pid0, s_pid1, tid);
    __syncthreads();
    stage1<4, 16, DW>(wsW + MP_OFF, mp_w, fW, mp_b, s_union, s_inp, wave, lane);
    if (tid < 32) s_q[tid] = 0.f;
    __syncthreads();

    for (int P = 0; P < 2; ++P) {
        const __bf16* Wa = wsW + (P ? W3_OFF : W1_OFF);
        const __bf16* Wb = wsW + (P ? W4_OFF : W2_OFF);
        const void* Wan = P ? w3 : w1;
        const void* Wbn = P ? w4 : w2;
        const void* ba = P ? b3 : b1;
        const void* bb = P ? b4 : b2;
        const void* rho = P ? rw2 : rw1;
        float* qp = s_q + P * 16;
        stage2s<3, DW>(0, Wa, Wan, fW, ba, s_union, s_inp, wave, lane);
        __syncthreads();
        stage3s<3, DW>(0, Wb, Wbn, fW, bb, rho, s_union, qp, wave, lane);
        __syncthreads();
        stage2s<2, DW>(3, Wa, Wan, fW, ba, s_union, s_inp, wave, lane);
        __syncthreads();
        stage3s<2, DW>(3, Wb, Wbn, fW, bb, rho, s_union, qp, wave, lane);
        __syncthreads();
    }

    if (tid < 16) {
        out[b0 + tid] = s_q[tid] + ldf(rb1, 0, fW);
        out[Btot + b0 + tid] = s_q[16 + tid] + ldf(rb2, 0, fW);
    }
}

extern "C" void kernel_launch(void* const* d_in, const int* in_sizes, int n_in,
                              void* d_out, int out_size, void* d_ws, size_t ws_size,
                              hipStream_t stream) {
    int B = out_size / 2;  // 16384

    const void *obs = nullptr, *act = nullptr, *ag = nullptr, *g = nullptr;
    const void *mp_w = nullptr, *mp_b = nullptr;
    const void *w1 = nullptr, *b1 = nullptr, *w2 = nullptr, *b2 = nullptr;
    const void *w3 = nullptr, *b3 = nullptr, *w4 = nullptr, *b4 = nullptr;
    const void *rw1 = nullptr, *rb1 = nullptr, *rw2 = nullptr, *rb2 = nullptr;
    const int *eA = nullptr, *eB = nullptr, *pred = nullptr, *inc = nullptr;
    int c30 = 0, c256 = 0, c1 = 0, c40k = 0, c65k = 0, c20 = 0;
    for (int i = 0; i < n_in; ++i) {
        int sz = in_sizes[i];
        const void* p = d_in[i];
        if (sz == B * 85) obs = p;
        else if (sz == B * 30) { if (c30++ == 0) ag = p; else g = p; }
        else if (sz == 5888) mp_w = p;
        else if (sz == 128) mp_b = p;
        else if (sz == 40192) { if (c40k++ == 0) w1 = p; else w3 = p; }
        else if (sz == 65536 || sz == B * 4) {
            int c = c65k++;
            if (c == 0) act = p; else if (c == 1) w2 = p; else w4 = p;
        }
        else if (sz == 256) {
            int c = c256++;
            if (c == 0) b1 = p; else if (c == 1) b2 = p; else if (c == 2) b3 = p;
            else if (c == 3) b4 = p; else if (c == 4) rw1 = p; else rw2 = p;
        }
        else if (sz == 1) { if (c1++ == 0) rb1 = p; else rb2 = p; }
        else if (sz == 40) pred = (const int*)p;
        else if (sz == 20) {
            int c = c20++;
            if (c == 0) eA = (const int*)p;
            else if (c == 1) eB = (const int*)p;
            else inc = (const int*)p;
        }
    }
    if (!obs || !act || !ag || !g || !mp_w || !mp_b || !w1 || !b1 || !w2 || !b2 ||
        !w3 || !b3 || !w4 || !b4 || !rw1 || !rb1 || !rw2 || !rb2 || !eA || !eB ||
        !pred || !inc) {
        obs = d_in[0]; act = d_in[1]; ag = d_in[2]; g = d_in[3];
        mp_w = d_in[4]; mp_b = d_in[5]; w1 = d_in[6]; b1 = d_in[7];
        w2 = d_in[8]; b2 = d_in[9]; w3 = d_in[10]; b3 = d_in[11];
        w4 = d_in[12]; b4 = d_in[13]; rw1 = d_in[14]; rb1 = d_in[15];
        rw2 = d_in[16]; rb2 = d_in[17];
        eA = (const int*)d_in[18]; eB = (const int*)d_in[19];
        pred = (const int*)d_in[20]; inc = (const int*)d_in[21];
    }

    float* out = (float*)d_out;
    __bf16* wsW = (__bf16*)d_ws;
    bool use_ws = ws_size >= WS_BYTES + 8;
    int* flags = (int*)((char*)d_ws + WS_BYTES);
    int grid = B / 16;

    if (use_ws) {
        swz<<<WS_TOTAL / 2048, 256, 0, stream>>>(
            mp_w, w1, w2, w3, w4, wsW, (const unsigned short*)obs, flags);
        gn_main<false><<<grid, 512, 0, stream>>>(
            obs, act, ag, g, mp_b, b1, b2, b3, b4, rw1, rb1, rw2, rb2,
            eA, eB, pred, inc, wsW, mp_w, w1, w2, w3, w4, flags, out, B);
    } else {
        gn_main<true><<<grid, 512, 0, stream>>>(
            obs, act, ag, g, mp_b, b1, b2, b3, b4, rw1, rb1, rw2, rb2,
            eA, eB, pred, inc, wsW, mp_w, w1, w2, w3, w4, flags, out, B);
    }
}